// Round 2
// baseline (537.528 us; speedup 1.0000x reference)
//
#include <hip/hip_runtime.h>
#include <hip/hip_bf16.h>
#include <stdint.h>

#define N_NODES 100000
#define N_EDGES 600000
#define D 128
#define EPS 1e-5f

typedef __attribute__((ext_vector_type(8))) short short8;
typedef __attribute__((ext_vector_type(16))) float floatx16;

// ---------- helpers ----------

__device__ __forceinline__ uint32_t pack_bf16_rne(float lo, float hi) {
    uint32_t ul = __builtin_bit_cast(uint32_t, lo);
    uint32_t uh = __builtin_bit_cast(uint32_t, hi);
    ul += 0x7fffu + ((ul >> 16) & 1u);
    uh += 0x7fffu + ((uh >> 16) & 1u);
    return (ul >> 16) | (uh & 0xffff0000u);
}

__device__ __forceinline__ unsigned short f32_to_bf16_rne(float f) {
    uint32_t u = __builtin_bit_cast(uint32_t, f);
    u += 0x7fffu + ((u >> 16) & 1u);
    return (unsigned short)(u >> 16);
}

// ---------- weight re-layout into 32x32x16 MFMA B-fragment order ----------
// frag element (s, t, lane, j)  <->  w[k = s*16 + (lane>>5)*8 + j][n = t*32 + (lane&31)]
__global__ void prep_weights(const float* __restrict__ w, unsigned short* __restrict__ out, int K) {
    int idx = blockIdx.x * blockDim.x + threadIdx.x;
    int total = K * 128;
    if (idx >= total) return;
    int j    = idx & 7;
    int lane = (idx >> 3) & 63;
    int t    = (idx >> 9) & 3;
    int s    = idx >> 11;
    int k = s * 16 + ((lane >> 5) << 3) + j;
    int n = t * 32 + (lane & 31);
    out[idx] = f32_to_bf16_rne(w[k * 128 + n]);
}

// ---------- message kernel: 32 edges per wave, private LDS tile, no block sync ----------
__launch_bounds__(256, 4)
__global__ void msg_kernel(const float* __restrict__ x,
                           const int* __restrict__ rowidx, const int* __restrict__ colidx,
                           const short8* __restrict__ w1f, const short8* __restrict__ w2f,
                           const float* __restrict__ b1, const float* __restrict__ b2,
                           float* __restrict__ agg) {
    __shared__ __align__(16) short h1[4][32 * 136];   // 34816 B/block -> 4 blocks/CU
    const int wave = threadIdx.x >> 6;
    const int lane = threadIdx.x & 63;
    const int l31  = lane & 31;
    const int half = lane >> 5;
    short* hl = h1[wave];

    const int ebase = (blockIdx.x * 4 + wave) * 32;
    const int e  = ebase + l31;
    const int ec = min(e, N_EDGES - 1);
    const int rI = rowidx[ec];
    const int cI = colidx[ec];

    const float* prow = x + (size_t)rI * D + half * 8;
    const float* pcol = x + (size_t)cI * D + half * 8;

    floatx16 acc[4];
#pragma unroll
    for (int t = 0; t < 4; ++t) acc[t] = (floatx16)0.0f;

    // GEMM1: [32 x 256] @ [256 x 128], K in 16 steps of 16
#pragma unroll
    for (int s = 0; s < 16; ++s) {
        const float* pa = (s < 8) ? prow : pcol;
        const int off = (s & 7) * 16;
        float4 a0 = *(const float4*)(pa + off);
        float4 a1 = *(const float4*)(pa + off + 4);
        union { short8 v; uint32_t u[4]; } fa;
        fa.u[0] = pack_bf16_rne(a0.x, a0.y); fa.u[1] = pack_bf16_rne(a0.z, a0.w);
        fa.u[2] = pack_bf16_rne(a1.x, a1.y); fa.u[3] = pack_bf16_rne(a1.z, a1.w);
#pragma unroll
        for (int t = 0; t < 4; ++t) {
            short8 wf = w1f[(s * 4 + t) * 64 + lane];
            acc[t] = __builtin_amdgcn_mfma_f32_32x32x16_bf16(fa.v, wf, acc[t], 0, 0, 0);
        }
    }

    // bias + ReLU + bf16, C-layout -> LDS row-major [32][136]
#pragma unroll
    for (int t = 0; t < 4; ++t) {
        float bias1 = b1[t * 32 + l31];
#pragma unroll
        for (int r = 0; r < 16; ++r) {
            int m = (r & 3) + 8 * (r >> 2) + 4 * half;
            float v = fmaxf(acc[t][r] + bias1, 0.0f);
            hl[m * 136 + t * 32 + l31] = (short)f32_to_bf16_rne(v);
        }
    }

    // GEMM2: [32 x 128] @ [128 x 128], K in 8 steps (wave-private LDS; waitcnt only)
    floatx16 acc2[4];
#pragma unroll
    for (int t = 0; t < 4; ++t) acc2[t] = (floatx16)0.0f;

#pragma unroll
    for (int s = 0; s < 8; ++s) {
        short8 af = *(const short8*)(hl + l31 * 136 + s * 16 + half * 8);
#pragma unroll
        for (int t = 0; t < 4; ++t) {
            short8 wf = w2f[(s * 4 + t) * 64 + lane];
            acc2[t] = __builtin_amdgcn_mfma_f32_32x32x16_bf16(af, wf, acc2[t], 0, 0, 0);
        }
    }

    // bias + scatter-add; each instr = 2x (32 contiguous floats)
    float bias2[4];
#pragma unroll
    for (int t = 0; t < 4; ++t) bias2[t] = b2[t * 32 + l31];

#pragma unroll
    for (int r = 0; r < 16; ++r) {
        int m = (r & 3) + 8 * (r >> 2) + 4 * half;
        int cm = __shfl(cI, m, 32);
        if (ebase + m < N_EDGES) {
            float* dst = agg + (size_t)cm * D + l31;
#pragma unroll
            for (int t = 0; t < 4; ++t)
                unsafeAtomicAdd(dst + t * 32, acc2[t][r] + bias2[t]);
        }
    }
}

// ---------- update kernel: 32 nodes per wave, fused LayerNorm + residual ----------
__launch_bounds__(256, 4)
__global__ void upd_kernel(const float* __restrict__ x, const float* __restrict__ agg,
                           const short8* __restrict__ w1f, const short8* __restrict__ w2f,
                           const float* __restrict__ b1, const float* __restrict__ b2,
                           const float* __restrict__ gamma, const float* __restrict__ beta,
                           float* __restrict__ out) {
    __shared__ __align__(16) short h1[4][32 * 136];
    const int wave = threadIdx.x >> 6;
    const int lane = threadIdx.x & 63;
    const int l31  = lane & 31;
    const int half = lane >> 5;
    short* hl = h1[wave];

    const int nbase = (blockIdx.x * 4 + wave) * 32;
    const int n = min(nbase + l31, N_NODES - 1);

    const float* px = x   + (size_t)n * D + half * 8;
    const float* pa = agg + (size_t)n * D + half * 8;

    floatx16 acc[4];
#pragma unroll
    for (int t = 0; t < 4; ++t) acc[t] = (floatx16)0.0f;

#pragma unroll
    for (int s = 0; s < 16; ++s) {
        const float* p = (s < 8) ? px : pa;
        const int off = (s & 7) * 16;
        float4 a0 = *(const float4*)(p + off);
        float4 a1 = *(const float4*)(p + off + 4);
        union { short8 v; uint32_t u[4]; } fa;
        fa.u[0] = pack_bf16_rne(a0.x, a0.y); fa.u[1] = pack_bf16_rne(a0.z, a0.w);
        fa.u[2] = pack_bf16_rne(a1.x, a1.y); fa.u[3] = pack_bf16_rne(a1.z, a1.w);
#pragma unroll
        for (int t = 0; t < 4; ++t) {
            short8 wf = w1f[(s * 4 + t) * 64 + lane];
            acc[t] = __builtin_amdgcn_mfma_f32_32x32x16_bf16(fa.v, wf, acc[t], 0, 0, 0);
        }
    }

#pragma unroll
    for (int t = 0; t < 4; ++t) {
        float bias1 = b1[t * 32 + l31];
#pragma unroll
        for (int r = 0; r < 16; ++r) {
            int m = (r & 3) + 8 * (r >> 2) + 4 * half;
            float v = fmaxf(acc[t][r] + bias1, 0.0f);
            hl[m * 136 + t * 32 + l31] = (short)f32_to_bf16_rne(v);
        }
    }

    floatx16 acc2[4];
#pragma unroll
    for (int t = 0; t < 4; ++t) acc2[t] = (floatx16)0.0f;

#pragma unroll
    for (int s = 0; s < 8; ++s) {
        short8 af = *(const short8*)(hl + l31 * 136 + s * 16 + half * 8);
#pragma unroll
        for (int t = 0; t < 4; ++t) {
            short8 wf = w2f[(s * 4 + t) * 64 + lane];
            acc2[t] = __builtin_amdgcn_mfma_f32_32x32x16_bf16(af, wf, acc2[t], 0, 0, 0);
        }
    }

    // fused LayerNorm + residual; row m lives in one 32-lane half -> butterfly
    float g4[4], be4[4], bias2[4];
#pragma unroll
    for (int t = 0; t < 4; ++t) {
        g4[t]    = gamma[t * 32 + l31];
        be4[t]   = beta[t * 32 + l31];
        bias2[t] = b2[t * 32 + l31];
    }

#pragma unroll
    for (int r = 0; r < 16; ++r) {
        float hv[4];
        float s1 = 0.0f, s2 = 0.0f;
#pragma unroll
        for (int t = 0; t < 4; ++t) {
            hv[t] = acc2[t][r] + bias2[t];
            s1 += hv[t];
            s2 += hv[t] * hv[t];
        }
#pragma unroll
        for (int mask = 1; mask < 32; mask <<= 1) {
            s1 += __shfl_xor(s1, mask);
            s2 += __shfl_xor(s2, mask);
        }
        float mean = s1 * (1.0f / 128.0f);
        float var  = s2 * (1.0f / 128.0f) - mean * mean;
        float rs   = rsqrtf(var + EPS);
        int m = (r & 3) + 8 * (r >> 2) + 4 * half;
        int node = nbase + m;
        if (node < N_NODES) {
            const float* xr = x + (size_t)node * D + l31;
            float* orow = out + (size_t)node * D + l31;
#pragma unroll
            for (int t = 0; t < 4; ++t) {
                float v = (hv[t] - mean) * rs * g4[t] + be4[t] + xr[t * 32];
                orow[t * 32] = v;
            }
        }
    }
}

// ---------- launch ----------
extern "C" void kernel_launch(void* const* d_in, const int* in_sizes, int n_in,
                              void* d_out, int out_size, void* d_ws, size_t ws_size,
                              hipStream_t stream) {
    const float* x     = (const float*)d_in[0];
    const int*   edge  = (const int*)d_in[1];
    const float* w_m1  = (const float*)d_in[2];
    const float* b_m1  = (const float*)d_in[3];
    const float* w_m2  = (const float*)d_in[4];
    const float* b_m2  = (const float*)d_in[5];
    const float* w_u1  = (const float*)d_in[6];
    const float* b_u1  = (const float*)d_in[7];
    const float* w_u2  = (const float*)d_in[8];
    const float* b_u2  = (const float*)d_in[9];
    const float* gamma = (const float*)d_in[10];
    const float* beta  = (const float*)d_in[11];
    float* out = (float*)d_out;

    char* ws = (char*)d_ws;
    float* agg = (float*)ws;
    const size_t aggBytes = (size_t)N_NODES * D * sizeof(float);
    unsigned short* wm1f = (unsigned short*)(ws + aggBytes);
    unsigned short* wm2f = wm1f + 256 * 128;
    unsigned short* wu1f = wm2f + 128 * 128;
    unsigned short* wu2f = wu1f + 256 * 128;

    hipMemsetAsync(agg, 0, aggBytes, stream);
    prep_weights<<<(256 * 128 + 255) / 256, 256, 0, stream>>>(w_m1, wm1f, 256);
    prep_weights<<<(128 * 128 + 255) / 256, 256, 0, stream>>>(w_m2, wm2f, 128);
    prep_weights<<<(256 * 128 + 255) / 256, 256, 0, stream>>>(w_u1, wu1f, 256);
    prep_weights<<<(128 * 128 + 255) / 256, 256, 0, stream>>>(w_u2, wu2f, 128);

    const int* rowi = edge;            // edge_index[0]
    const int* coli = edge + N_EDGES;  // edge_index[1]

    // 32 edges/wave * 4 waves = 128 edges per block
    msg_kernel<<<(N_EDGES + 127) / 128, 256, 0, stream>>>(
        x, rowi, coli, (const short8*)wm1f, (const short8*)wm2f, b_m1, b_m2, agg);
    upd_kernel<<<(N_NODES + 127) / 128, 256, 0, stream>>>(
        x, agg, (const short8*)wu1f, (const short8*)wu2f, b_u1, b_u2, gamma, beta, out);
}

// Round 4
// 424.240 us; speedup vs baseline: 1.2670x; 1.2670x over previous
//
#include <hip/hip_runtime.h>
#include <hip/hip_bf16.h>
#include <stdint.h>

#define N_NODES 100000
#define N_EDGES 600000
#define D 128
#define EPS 1e-5f

typedef __attribute__((ext_vector_type(8))) short short8;
typedef __attribute__((ext_vector_type(16))) float floatx16;

// ---------- helpers ----------

__device__ __forceinline__ uint32_t pack_bf16_rne(float lo, float hi) {
    uint32_t ul = __builtin_bit_cast(uint32_t, lo);
    uint32_t uh = __builtin_bit_cast(uint32_t, hi);
    ul += 0x7fffu + ((ul >> 16) & 1u);
    uh += 0x7fffu + ((uh >> 16) & 1u);
    return (ul >> 16) | (uh & 0xffff0000u);
}

__device__ __forceinline__ unsigned short f32_to_bf16_rne(float f) {
    uint32_t u = __builtin_bit_cast(uint32_t, f);
    u += 0x7fffu + ((u >> 16) & 1u);
    return (unsigned short)(u >> 16);
}

// packed bf16x2 atomic add, straight to the gfx950 instruction
__device__ __forceinline__ void atomic_pk_add_bf16(void* dst, uint32_t packed) {
    asm volatile("global_atomic_pk_add_bf16 %0, %1, off" :: "v"(dst), "v"(packed) : "memory");
}

// ---------- weight re-layout into 32x32x16 MFMA B-fragment order ----------
// frag element (s, t, lane, j)  <->  w[k = s*16 + (lane>>5)*8 + j][n = t*32 + (lane&31)]
// permute!=0: for k>=128 remap k to match the permuted bf16 agg layout:
//   stored agg position p holds original col c(p) = ((p>>1)&31) + 32*(2*(p>>6) + (p&1))
__global__ void prep_weights(const float* __restrict__ w, unsigned short* __restrict__ out,
                             int K, int permute) {
    int idx = blockIdx.x * blockDim.x + threadIdx.x;
    int total = K * 128;
    if (idx >= total) return;
    int j    = idx & 7;
    int lane = (idx >> 3) & 63;
    int t    = (idx >> 9) & 3;
    int s    = idx >> 11;
    int k = s * 16 + ((lane >> 5) << 3) + j;
    if (permute && k >= 128) {
        int p = k - 128;
        k = 128 + ((p >> 1) & 31) + 32 * (2 * (p >> 6) + (p & 1));
    }
    int n = t * 32 + (lane & 31);
    out[idx] = f32_to_bf16_rne(w[k * 128 + n]);
}

// ---------- message kernel: 32 edges per wave, pk_add_bf16 scatter ----------
__launch_bounds__(256, 4)
__global__ void msg_kernel(const float* __restrict__ x,
                           const int* __restrict__ rowidx, const int* __restrict__ colidx,
                           const short8* __restrict__ w1f, const short8* __restrict__ w2f,
                           const float* __restrict__ b1, const float* __restrict__ b2,
                           uint32_t* __restrict__ agg) {
    __shared__ __align__(16) short h1[4][32 * 136];   // 34816 B/block -> 4 blocks/CU
    const int wave = threadIdx.x >> 6;
    const int lane = threadIdx.x & 63;
    const int l31  = lane & 31;
    const int half = lane >> 5;
    short* hl = h1[wave];

    const int ebase = (blockIdx.x * 4 + wave) * 32;
    const int e  = ebase + l31;
    const int ec = min(e, N_EDGES - 1);
    const int rI = rowidx[ec];
    const int cI = colidx[ec];

    const float* prow = x + (size_t)rI * D + half * 8;
    const float* pcol = x + (size_t)cI * D + half * 8;

    floatx16 acc[4];
#pragma unroll
    for (int t = 0; t < 4; ++t) acc[t] = (floatx16)0.0f;

    // GEMM1: [32 x 256] @ [256 x 128], K in 16 steps of 16
#pragma unroll
    for (int s = 0; s < 16; ++s) {
        const float* pa = (s < 8) ? prow : pcol;
        const int off = (s & 7) * 16;
        float4 a0 = *(const float4*)(pa + off);
        float4 a1 = *(const float4*)(pa + off + 4);
        union { short8 v; uint32_t u[4]; } fa;
        fa.u[0] = pack_bf16_rne(a0.x, a0.y); fa.u[1] = pack_bf16_rne(a0.z, a0.w);
        fa.u[2] = pack_bf16_rne(a1.x, a1.y); fa.u[3] = pack_bf16_rne(a1.z, a1.w);
#pragma unroll
        for (int t = 0; t < 4; ++t) {
            short8 wf = w1f[(s * 4 + t) * 64 + lane];
            acc[t] = __builtin_amdgcn_mfma_f32_32x32x16_bf16(fa.v, wf, acc[t], 0, 0, 0);
        }
    }

    // bias + ReLU + bf16, C-layout -> LDS row-major [32][136]
#pragma unroll
    for (int t = 0; t < 4; ++t) {
        float bias1 = b1[t * 32 + l31];
#pragma unroll
        for (int r = 0; r < 16; ++r) {
            int m = (r & 3) + 8 * (r >> 2) + 4 * half;
            float v = fmaxf(acc[t][r] + bias1, 0.0f);
            hl[m * 136 + t * 32 + l31] = (short)f32_to_bf16_rne(v);
        }
    }

    // GEMM2: [32 x 128] @ [128 x 128], K in 8 steps (wave-private LDS)
    floatx16 acc2[4];
#pragma unroll
    for (int t = 0; t < 4; ++t) acc2[t] = (floatx16)0.0f;

#pragma unroll
    for (int s = 0; s < 8; ++s) {
        short8 af = *(const short8*)(hl + l31 * 136 + s * 16 + half * 8);
#pragma unroll
        for (int t = 0; t < 4; ++t) {
            short8 wf = w2f[(s * 4 + t) * 64 + lane];
            acc2[t] = __builtin_amdgcn_mfma_f32_32x32x16_bf16(af, wf, acc2[t], 0, 0, 0);
        }
    }

    // bias + pk_add_bf16 scatter into permuted bf16 agg.
    // Per r, each half writes one row: 32 consecutive dwords (coalesced 128B) x2.
    float bias2[4];
#pragma unroll
    for (int t = 0; t < 4; ++t) bias2[t] = b2[t * 32 + l31];

#pragma unroll
    for (int r = 0; r < 16; ++r) {
        int m = (r & 3) + 8 * (r >> 2) + 4 * half;
        int cm = __shfl(cI, m, 32);
        if (ebase + m < N_EDGES) {
            uint32_t p0 = pack_bf16_rne(acc2[0][r] + bias2[0], acc2[1][r] + bias2[1]);
            uint32_t p1 = pack_bf16_rne(acc2[2][r] + bias2[2], acc2[3][r] + bias2[3]);
            uint32_t* dst = agg + (size_t)cm * 64 + l31;
            atomic_pk_add_bf16(dst,      p0);
            atomic_pk_add_bf16(dst + 32, p1);
        }
    }
}

// ---------- update kernel: 32 nodes per wave, bf16 agg input, fused LN + residual ----------
__launch_bounds__(256, 4)
__global__ void upd_kernel(const float* __restrict__ x, const unsigned short* __restrict__ aggB,
                           const short8* __restrict__ w1f, const short8* __restrict__ w2f,
                           const float* __restrict__ b1, const float* __restrict__ b2,
                           const float* __restrict__ gamma, const float* __restrict__ beta,
                           float* __restrict__ out) {
    __shared__ __align__(16) short h1[4][32 * 136];
    const int wave = threadIdx.x >> 6;
    const int lane = threadIdx.x & 63;
    const int l31  = lane & 31;
    const int half = lane >> 5;
    short* hl = h1[wave];

    const int nbase = (blockIdx.x * 4 + wave) * 32;
    const int n = min(nbase + l31, N_NODES - 1);

    const float* px = x + (size_t)n * D + half * 8;
    const unsigned short* pagg = aggB + (size_t)n * D + half * 8;

    floatx16 acc[4];
#pragma unroll
    for (int t = 0; t < 4; ++t) acc[t] = (floatx16)0.0f;

#pragma unroll
    for (int s = 0; s < 16; ++s) {
        union { short8 v; uint32_t u[4]; } fa;
        if (s < 8) {
            const int off = s * 16;
            float4 a0 = *(const float4*)(px + off);
            float4 a1 = *(const float4*)(px + off + 4);
            fa.u[0] = pack_bf16_rne(a0.x, a0.y); fa.u[1] = pack_bf16_rne(a0.z, a0.w);
            fa.u[2] = pack_bf16_rne(a1.x, a1.y); fa.u[3] = pack_bf16_rne(a1.z, a1.w);
        } else {
            fa.v = *(const short8*)(pagg + (s - 8) * 16);  // permuted layout; w1f matches
        }
#pragma unroll
        for (int t = 0; t < 4; ++t) {
            short8 wf = w1f[(s * 4 + t) * 64 + lane];
            acc[t] = __builtin_amdgcn_mfma_f32_32x32x16_bf16(fa.v, wf, acc[t], 0, 0, 0);
        }
    }

#pragma unroll
    for (int t = 0; t < 4; ++t) {
        float bias1 = b1[t * 32 + l31];
#pragma unroll
        for (int r = 0; r < 16; ++r) {
            int m = (r & 3) + 8 * (r >> 2) + 4 * half;
            float v = fmaxf(acc[t][r] + bias1, 0.0f);
            hl[m * 136 + t * 32 + l31] = (short)f32_to_bf16_rne(v);
        }
    }

    floatx16 acc2[4];
#pragma unroll
    for (int t = 0; t < 4; ++t) acc2[t] = (floatx16)0.0f;

#pragma unroll
    for (int s = 0; s < 8; ++s) {
        short8 af = *(const short8*)(hl + l31 * 136 + s * 16 + half * 8);
#pragma unroll
        for (int t = 0; t < 4; ++t) {
            short8 wf = w2f[(s * 4 + t) * 64 + lane];
            acc2[t] = __builtin_amdgcn_mfma_f32_32x32x16_bf16(af, wf, acc2[t], 0, 0, 0);
        }
    }

    // fused LayerNorm + residual; row m lives in one 32-lane half -> butterfly
    float g4[4], be4[4], bias2[4];
#pragma unroll
    for (int t = 0; t < 4; ++t) {
        g4[t]    = gamma[t * 32 + l31];
        be4[t]   = beta[t * 32 + l31];
        bias2[t] = b2[t * 32 + l31];
    }

#pragma unroll
    for (int r = 0; r < 16; ++r) {
        float hv[4];
        float s1 = 0.0f, s2 = 0.0f;
#pragma unroll
        for (int t = 0; t < 4; ++t) {
            hv[t] = acc2[t][r] + bias2[t];
            s1 += hv[t];
            s2 += hv[t] * hv[t];
        }
#pragma unroll
        for (int mask = 1; mask < 32; mask <<= 1) {
            s1 += __shfl_xor(s1, mask);
            s2 += __shfl_xor(s2, mask);
        }
        float mean = s1 * (1.0f / 128.0f);
        float var  = s2 * (1.0f / 128.0f) - mean * mean;
        float rs   = rsqrtf(var + EPS);
        int m = (r & 3) + 8 * (r >> 2) + 4 * half;
        int node = nbase + m;
        if (node < N_NODES) {
            const float* xr = x + (size_t)node * D + l31;
            float* orow = out + (size_t)node * D + l31;
#pragma unroll
            for (int t = 0; t < 4; ++t) {
                float v = (hv[t] - mean) * rs * g4[t] + be4[t] + xr[t * 32];
                orow[t * 32] = v;
            }
        }
    }
}

// ---------- launch ----------
extern "C" void kernel_launch(void* const* d_in, const int* in_sizes, int n_in,
                              void* d_out, int out_size, void* d_ws, size_t ws_size,
                              hipStream_t stream) {
    const float* x     = (const float*)d_in[0];
    const int*   edge  = (const int*)d_in[1];
    const float* w_m1  = (const float*)d_in[2];
    const float* b_m1  = (const float*)d_in[3];
    const float* w_m2  = (const float*)d_in[4];
    const float* b_m2  = (const float*)d_in[5];
    const float* w_u1  = (const float*)d_in[6];
    const float* b_u1  = (const float*)d_in[7];
    const float* w_u2  = (const float*)d_in[8];
    const float* b_u2  = (const float*)d_in[9];
    const float* gamma = (const float*)d_in[10];
    const float* beta  = (const float*)d_in[11];
    float* out = (float*)d_out;

    char* ws = (char*)d_ws;
    unsigned short* aggB = (unsigned short*)ws;                 // bf16 [N_NODES][128], permuted cols
    const size_t aggBytes = (size_t)N_NODES * D * sizeof(unsigned short);
    unsigned short* wm1f = (unsigned short*)(ws + aggBytes);
    unsigned short* wm2f = wm1f + 256 * 128;
    unsigned short* wu1f = wm2f + 128 * 128;
    unsigned short* wu2f = wu1f + 256 * 128;

    hipMemsetAsync(aggB, 0, aggBytes, stream);
    prep_weights<<<(256 * 128 + 255) / 256, 256, 0, stream>>>(w_m1, wm1f, 256, 0);
    prep_weights<<<(128 * 128 + 255) / 256, 256, 0, stream>>>(w_m2, wm2f, 128, 0);
    prep_weights<<<(256 * 128 + 255) / 256, 256, 0, stream>>>(w_u1, wu1f, 256, 1);  // permuted agg half
    prep_weights<<<(128 * 128 + 255) / 256, 256, 0, stream>>>(w_u2, wu2f, 128, 0);

    const int* rowi = edge;            // edge_index[0]
    const int* coli = edge + N_EDGES;  // edge_index[1]

    msg_kernel<<<(N_EDGES + 127) / 128, 256, 0, stream>>>(
        x, rowi, coli, (const short8*)wm1f, (const short8*)wm2f, b_m1, b_m2,
        (uint32_t*)aggB);
    upd_kernel<<<(N_NODES + 127) / 128, 256, 0, stream>>>(
        x, aggB, (const short8*)wu1f, (const short8*)wu2f, b_u1, b_u2, gamma, beta, out);
}

// Round 5
// 350.637 us; speedup vs baseline: 1.5330x; 1.2099x over previous
//
#include <hip/hip_runtime.h>
#include <hip/hip_bf16.h>
#include <stdint.h>

#define N_NODES 100000
#define N_EDGES 600000
#define D 128
#define EPS 1e-5f

typedef __attribute__((ext_vector_type(8))) short short8;
typedef __attribute__((ext_vector_type(16))) float floatx16;

// ---------- helpers ----------

__device__ __forceinline__ uint32_t pack_bf16_rne(float lo, float hi) {
    uint32_t ul = __builtin_bit_cast(uint32_t, lo);
    uint32_t uh = __builtin_bit_cast(uint32_t, hi);
    ul += 0x7fffu + ((ul >> 16) & 1u);
    uh += 0x7fffu + ((uh >> 16) & 1u);
    return (ul >> 16) | (uh & 0xffff0000u);
}

__device__ __forceinline__ unsigned short f32_to_bf16_rne(float f) {
    uint32_t u = __builtin_bit_cast(uint32_t, f);
    u += 0x7fffu + ((u >> 16) & 1u);
    return (unsigned short)(u >> 16);
}

// packed bf16x2 atomic add (gfx950 instruction)
__device__ __forceinline__ void atomic_pk_add_bf16(void* dst, uint32_t packed) {
    asm volatile("global_atomic_pk_add_bf16 %0, %1, off" :: "v"(dst), "v"(packed) : "memory");
}

// ---------- weight re-layout into 32x32x16 MFMA B-fragment order ----------
// frag element (s, t, lane, j)  <->  w[k = s*16 + (lane>>5)*8 + j][n = t*32 + (lane&31)]
// permute!=0: for k>=128 remap k to match the permuted bf16 agg layout:
//   stored agg position p holds original col c(p) = ((p>>1)&31) + 32*(2*(p>>6) + (p&1))
__global__ void prep_weights(const float* __restrict__ w, unsigned short* __restrict__ out,
                             int K, int permute) {
    int idx = blockIdx.x * blockDim.x + threadIdx.x;
    int total = K * 128;
    if (idx >= total) return;
    int j    = idx & 7;
    int lane = (idx >> 3) & 63;
    int t    = (idx >> 9) & 3;
    int s    = idx >> 11;
    int k = s * 16 + ((lane >> 5) << 3) + j;
    if (permute && k >= 128) {
        int p = k - 128;
        k = 128 + ((p >> 1) & 31) + 32 * (2 * (p >> 6) + (p & 1));
    }
    int n = t * 32 + (lane & 31);
    out[idx] = f32_to_bf16_rne(w[k * 128 + n]);
}

// ---------- xform kernel: XT = x @ W_top, XB = x @ W_bot + b1, bf16 [node][256] ----------
// Output row-major; msg kernel's lane reads 16B chunks at k = half*8 + s*16.
__launch_bounds__(256, 2)
__global__ void xform_kernel(const float* __restrict__ x, const short8* __restrict__ w1f,
                             const float* __restrict__ b1, unsigned short* __restrict__ xtb) {
    __shared__ __align__(16) short h1[4][32 * 136];
    const int wave = threadIdx.x >> 6;
    const int lane = threadIdx.x & 63;
    const int l31  = lane & 31;
    const int half = lane >> 5;
    short* hl = h1[wave];

    const int nbase = (blockIdx.x * 4 + wave) * 32;
    const int n = min(nbase + l31, N_NODES - 1);
    const float* px = x + (size_t)n * D + half * 8;

    // load + pack all A-fragments once (reused for both passes)
    union { short8 v; uint32_t u[4]; } fa[8];
#pragma unroll
    for (int s = 0; s < 8; ++s) {
        const int off = s * 16;
        float4 a0 = *(const float4*)(px + off);
        float4 a1 = *(const float4*)(px + off + 4);
        fa[s].u[0] = pack_bf16_rne(a0.x, a0.y); fa[s].u[1] = pack_bf16_rne(a0.z, a0.w);
        fa[s].u[2] = pack_bf16_rne(a1.x, a1.y); fa[s].u[3] = pack_bf16_rne(a1.z, a1.w);
    }

#pragma unroll
    for (int p = 0; p < 2; ++p) {
        floatx16 acc[4];
#pragma unroll
        for (int t = 0; t < 4; ++t) acc[t] = (floatx16)0.0f;
#pragma unroll
        for (int s = 0; s < 8; ++s) {
#pragma unroll
            for (int t = 0; t < 4; ++t) {
                short8 wf = w1f[((p * 8 + s) * 4 + t) * 64 + lane];
                acc[t] = __builtin_amdgcn_mfma_f32_32x32x16_bf16(fa[s].v, wf, acc[t], 0, 0, 0);
            }
        }
        // C-layout -> LDS row-major [32][136]; bias (b1) folded into XB pass only
#pragma unroll
        for (int t = 0; t < 4; ++t) {
            float bias = p ? b1[t * 32 + l31] : 0.0f;
#pragma unroll
            for (int r = 0; r < 16; ++r) {
                int m = (r & 3) + 8 * (r >> 2) + 4 * half;
                hl[m * 136 + t * 32 + l31] = (short)f32_to_bf16_rne(acc[t][r] + bias);
            }
        }
        // coalesced store: 32 rows x 128 shorts -> xtb[node][p*128 ..]
#pragma unroll
        for (int it = 0; it < 8; ++it) {
            int off = it * 512 + lane * 8;       // shorts
            int row = off >> 7;
            int col = off & 127;
            if (nbase + row < N_NODES) {
                short8 v = *(const short8*)(hl + row * 136 + col);
                *(short8*)(xtb + (size_t)(nbase + row) * 256 + p * 128 + col) = v;
            }
        }
    }
}

// ---------- message kernel: gather XT[row]+XB[col], ReLU, GEMM2, pk_add scatter ----------
__launch_bounds__(256, 4)
__global__ void msg_kernel(const unsigned short* __restrict__ xtb,
                           const int* __restrict__ rowidx, const int* __restrict__ colidx,
                           const short8* __restrict__ w2f,
                           const float* __restrict__ b2,
                           uint32_t* __restrict__ agg) {
    const int lane = threadIdx.x & 63;
    const int l31  = lane & 31;
    const int half = lane >> 5;

    const int ebase = (blockIdx.x * 4 + (threadIdx.x >> 6)) * 32;
    const int e  = ebase + l31;
    const int ec = min(e, N_EDGES - 1);
    const int rI = rowidx[ec];
    const int cI = colidx[ec];

    const unsigned short* pt = xtb + (size_t)rI * 256 + half * 8;        // XT[row]
    const unsigned short* pb = xtb + (size_t)cI * 256 + 128 + half * 8;  // XB[col] (bias folded)

    floatx16 acc2[4];
#pragma unroll
    for (int t = 0; t < 4; ++t) acc2[t] = (floatx16)0.0f;

#pragma unroll
    for (int s = 0; s < 8; ++s) {
        union { short8 v; uint32_t u[4]; } ta, tb, h;
        ta.v = *(const short8*)(pt + s * 16);
        tb.v = *(const short8*)(pb + s * 16);
#pragma unroll
        for (int d = 0; d < 4; ++d) {
            uint32_t au = ta.u[d], bu = tb.u[d];
            float lo = __builtin_bit_cast(float, au << 16) + __builtin_bit_cast(float, bu << 16);
            float hi = __builtin_bit_cast(float, au & 0xffff0000u) +
                       __builtin_bit_cast(float, bu & 0xffff0000u);
            lo = fmaxf(lo, 0.0f);
            hi = fmaxf(hi, 0.0f);
            h.u[d] = pack_bf16_rne(lo, hi);
        }
#pragma unroll
        for (int t = 0; t < 4; ++t) {
            short8 wf = w2f[(s * 4 + t) * 64 + lane];
            acc2[t] = __builtin_amdgcn_mfma_f32_32x32x16_bf16(h.v, wf, acc2[t], 0, 0, 0);
        }
    }

    // bias + pk_add_bf16 scatter into permuted bf16 agg (2x 128B coalesced per r)
    float bias2[4];
#pragma unroll
    for (int t = 0; t < 4; ++t) bias2[t] = b2[t * 32 + l31];

#pragma unroll
    for (int r = 0; r < 16; ++r) {
        int m = (r & 3) + 8 * (r >> 2) + 4 * half;
        int cm = __shfl(cI, m, 32);
        if (ebase + m < N_EDGES) {
            uint32_t p0 = pack_bf16_rne(acc2[0][r] + bias2[0], acc2[1][r] + bias2[1]);
            uint32_t p1 = pack_bf16_rne(acc2[2][r] + bias2[2], acc2[3][r] + bias2[3]);
            uint32_t* dst = agg + (size_t)cm * 64 + l31;
            atomic_pk_add_bf16(dst,      p0);
            atomic_pk_add_bf16(dst + 32, p1);
        }
    }
}

// ---------- update kernel: 32 nodes per wave, bf16 agg input, fused LN + residual ----------
__launch_bounds__(256, 4)
__global__ void upd_kernel(const float* __restrict__ x, const unsigned short* __restrict__ aggB,
                           const short8* __restrict__ w1f, const short8* __restrict__ w2f,
                           const float* __restrict__ b1, const float* __restrict__ b2,
                           const float* __restrict__ gamma, const float* __restrict__ beta,
                           float* __restrict__ out) {
    __shared__ __align__(16) short h1[4][32 * 136];
    const int wave = threadIdx.x >> 6;
    const int lane = threadIdx.x & 63;
    const int l31  = lane & 31;
    const int half = lane >> 5;
    short* hl = h1[wave];

    const int nbase = (blockIdx.x * 4 + wave) * 32;
    const int n = min(nbase + l31, N_NODES - 1);

    const float* px = x + (size_t)n * D + half * 8;
    const unsigned short* pagg = aggB + (size_t)n * D + half * 8;

    floatx16 acc[4];
#pragma unroll
    for (int t = 0; t < 4; ++t) acc[t] = (floatx16)0.0f;

#pragma unroll
    for (int s = 0; s < 16; ++s) {
        union { short8 v; uint32_t u[4]; } fa;
        if (s < 8) {
            const int off = s * 16;
            float4 a0 = *(const float4*)(px + off);
            float4 a1 = *(const float4*)(px + off + 4);
            fa.u[0] = pack_bf16_rne(a0.x, a0.y); fa.u[1] = pack_bf16_rne(a0.z, a0.w);
            fa.u[2] = pack_bf16_rne(a1.x, a1.y); fa.u[3] = pack_bf16_rne(a1.z, a1.w);
        } else {
            fa.v = *(const short8*)(pagg + (s - 8) * 16);  // permuted layout; w1f matches
        }
#pragma unroll
        for (int t = 0; t < 4; ++t) {
            short8 wf = w1f[(s * 4 + t) * 64 + lane];
            acc[t] = __builtin_amdgcn_mfma_f32_32x32x16_bf16(fa.v, wf, acc[t], 0, 0, 0);
        }
    }

#pragma unroll
    for (int t = 0; t < 4; ++t) {
        float bias1 = b1[t * 32 + l31];
#pragma unroll
        for (int r = 0; r < 16; ++r) {
            int m = (r & 3) + 8 * (r >> 2) + 4 * half;
            float v = fmaxf(acc[t][r] + bias1, 0.0f);
            hl[m * 136 + t * 32 + l31] = (short)f32_to_bf16_rne(v);
        }
    }

    floatx16 acc2[4];
#pragma unroll
    for (int t = 0; t < 4; ++t) acc2[t] = (floatx16)0.0f;

#pragma unroll
    for (int s = 0; s < 8; ++s) {
        short8 af = *(const short8*)(hl + l31 * 136 + s * 16 + half * 8);
#pragma unroll
        for (int t = 0; t < 4; ++t) {
            short8 wf = w2f[(s * 4 + t) * 64 + lane];
            acc2[t] = __builtin_amdgcn_mfma_f32_32x32x16_bf16(af, wf, acc2[t], 0, 0, 0);
        }
    }

    // fused LayerNorm + residual; row m lives in one 32-lane half -> butterfly
    float g4[4], be4[4], bias2[4];
#pragma unroll
    for (int t = 0; t < 4; ++t) {
        g4[t]    = gamma[t * 32 + l31];
        be4[t]   = beta[t * 32 + l31];
        bias2[t] = b2[t * 32 + l31];
    }

#pragma unroll
    for (int r = 0; r < 16; ++r) {
        float hv[4];
        float s1 = 0.0f, s2 = 0.0f;
#pragma unroll
        for (int t = 0; t < 4; ++t) {
            hv[t] = acc2[t][r] + bias2[t];
            s1 += hv[t];
            s2 += hv[t] * hv[t];
        }
#pragma unroll
        for (int mask = 1; mask < 32; mask <<= 1) {
            s1 += __shfl_xor(s1, mask);
            s2 += __shfl_xor(s2, mask);
        }
        float mean = s1 * (1.0f / 128.0f);
        float var  = s2 * (1.0f / 128.0f) - mean * mean;
        float rs   = rsqrtf(var + EPS);
        int m = (r & 3) + 8 * (r >> 2) + 4 * half;
        int node = nbase + m;
        if (node < N_NODES) {
            const float* xr = x + (size_t)node * D + l31;
            float* orow = out + (size_t)node * D + l31;
#pragma unroll
            for (int t = 0; t < 4; ++t) {
                float v = (hv[t] - mean) * rs * g4[t] + be4[t] + xr[t * 32];
                orow[t * 32] = v;
            }
        }
    }
}

// ---------- launch ----------
extern "C" void kernel_launch(void* const* d_in, const int* in_sizes, int n_in,
                              void* d_out, int out_size, void* d_ws, size_t ws_size,
                              hipStream_t stream) {
    const float* x     = (const float*)d_in[0];
    const int*   edge  = (const int*)d_in[1];
    const float* w_m1  = (const float*)d_in[2];
    const float* b_m1  = (const float*)d_in[3];
    const float* w_m2  = (const float*)d_in[4];
    const float* b_m2  = (const float*)d_in[5];
    const float* w_u1  = (const float*)d_in[6];
    const float* b_u1  = (const float*)d_in[7];
    const float* w_u2  = (const float*)d_in[8];
    const float* b_u2  = (const float*)d_in[9];
    const float* gamma = (const float*)d_in[10];
    const float* beta  = (const float*)d_in[11];
    float* out = (float*)d_out;

    char* ws = (char*)d_ws;
    unsigned short* xtb = (unsigned short*)ws;                  // bf16 [N_NODES][256]: XT | XB+b1
    const size_t xtbBytes = (size_t)N_NODES * 256 * sizeof(unsigned short);
    unsigned short* aggB = (unsigned short*)(ws + xtbBytes);    // bf16 [N_NODES][128], permuted cols
    const size_t aggBytes = (size_t)N_NODES * D * sizeof(unsigned short);
    unsigned short* wm1f = (unsigned short*)(ws + xtbBytes + aggBytes);
    unsigned short* wm2f = wm1f + 256 * 128;
    unsigned short* wu1f = wm2f + 128 * 128;
    unsigned short* wu2f = wu1f + 256 * 128;

    hipMemsetAsync(aggB, 0, aggBytes, stream);
    prep_weights<<<(256 * 128 + 255) / 256, 256, 0, stream>>>(w_m1, wm1f, 256, 0);
    prep_weights<<<(128 * 128 + 255) / 256, 256, 0, stream>>>(w_m2, wm2f, 128, 0);
    prep_weights<<<(256 * 128 + 255) / 256, 256, 0, stream>>>(w_u1, wu1f, 256, 1);  // permuted agg half
    prep_weights<<<(128 * 128 + 255) / 256, 256, 0, stream>>>(w_u2, wu2f, 128, 0);

    const int* rowi = edge;            // edge_index[0]
    const int* coli = edge + N_EDGES;  // edge_index[1]

    xform_kernel<<<(N_NODES + 127) / 128, 256, 0, stream>>>(
        x, (const short8*)wm1f, b_m1, xtb);
    msg_kernel<<<(N_EDGES + 127) / 128, 256, 0, stream>>>(
        xtb, rowi, coli, (const short8*)wm2f, b_m2, (uint32_t*)aggB);
    upd_kernel<<<(N_NODES + 127) / 128, 256, 0, stream>>>(
        x, aggB, (const short8*)wu1f, (const short8*)wu2f, b_u1, b_u2, gamma, beta, out);
}

// Round 6
// 350.571 us; speedup vs baseline: 1.5333x; 1.0002x over previous
//
#include <hip/hip_runtime.h>
#include <hip/hip_bf16.h>
#include <stdint.h>

#define N_NODES 100000
#define N_EDGES 600000
#define D 128
#define EPS 1e-5f
#define SCAN_BS 512

typedef __attribute__((ext_vector_type(8))) short short8;
typedef __attribute__((ext_vector_type(16))) float floatx16;

// ---------- helpers ----------

__device__ __forceinline__ uint32_t pack_bf16_rne(float lo, float hi) {
    uint32_t ul = __builtin_bit_cast(uint32_t, lo);
    uint32_t uh = __builtin_bit_cast(uint32_t, hi);
    ul += 0x7fffu + ((ul >> 16) & 1u);
    uh += 0x7fffu + ((uh >> 16) & 1u);
    return (ul >> 16) | (uh & 0xffff0000u);
}

__device__ __forceinline__ unsigned short f32_to_bf16_rne(float f) {
    uint32_t u = __builtin_bit_cast(uint32_t, f);
    u += 0x7fffu + ((u >> 16) & 1u);
    return (unsigned short)(u >> 16);
}

// packed bf16x2 atomic add (gfx950 instruction)
__device__ __forceinline__ void atomic_pk_add_bf16(void* dst, uint32_t packed) {
    asm volatile("global_atomic_pk_add_bf16 %0, %1, off" :: "v"(dst), "v"(packed) : "memory");
}

// ---------- counting sort of edges by destination (col) ----------

__global__ void hist_kernel(const int* __restrict__ col, int* __restrict__ count) {
    int e = blockIdx.x * blockDim.x + threadIdx.x;
    if (e < N_EDGES) atomicAdd(&count[col[e]], 1);
}

__global__ void scanA_kernel(const int* __restrict__ count, int* __restrict__ base,
                             int* __restrict__ bsum) {
    __shared__ int tmp[SCAN_BS];
    int g = blockIdx.x * SCAN_BS + threadIdx.x;
    int v = (g < N_NODES) ? count[g] : 0;
    tmp[threadIdx.x] = v;
    __syncthreads();
    int acc = v;
#pragma unroll
    for (int off = 1; off < SCAN_BS; off <<= 1) {
        int add = (threadIdx.x >= off) ? tmp[threadIdx.x - off] : 0;
        __syncthreads();
        acc += add;
        tmp[threadIdx.x] = acc;
        __syncthreads();
    }
    if (g < N_NODES) base[g] = acc - v;                 // exclusive within block
    if (threadIdx.x == SCAN_BS - 1) bsum[blockIdx.x] = acc;
}

__global__ void scanB_kernel(int* __restrict__ bsum, int nb) {
    __shared__ int tmp[256];
    int v = (threadIdx.x < nb) ? bsum[threadIdx.x] : 0;
    tmp[threadIdx.x] = v;
    __syncthreads();
    int acc = v;
#pragma unroll
    for (int off = 1; off < 256; off <<= 1) {
        int add = (threadIdx.x >= off) ? tmp[threadIdx.x - off] : 0;
        __syncthreads();
        acc += add;
        tmp[threadIdx.x] = acc;
        __syncthreads();
    }
    if (threadIdx.x < nb) bsum[threadIdx.x] = acc - v;  // exclusive block offsets
}

__global__ void scanC_kernel(int* __restrict__ base, const int* __restrict__ bsum,
                             int* __restrict__ cursor) {
    int g = blockIdx.x * SCAN_BS + threadIdx.x;
    if (g < N_NODES) {
        int b = base[g] + bsum[blockIdx.x];
        base[g] = b;
        cursor[g] = b;
    }
}

__global__ void scatter_kernel(const int* __restrict__ row, const int* __restrict__ col,
                               int* __restrict__ cursor,
                               int* __restrict__ srow, int* __restrict__ scol) {
    int e = blockIdx.x * blockDim.x + threadIdx.x;
    if (e < N_EDGES) {
        int c = col[e];
        int p = atomicAdd(&cursor[c], 1);
        srow[p] = row[e];
        scol[p] = c;
    }
}

// ---------- weight re-layout into 32x32x16 MFMA B-fragment order ----------
// frag element (s, t, lane, j)  <->  w[k = s*16 + (lane>>5)*8 + j][n = t*32 + (lane&31)]
// permute!=0: for k>=128 remap k to match the permuted bf16 agg layout:
//   stored agg position p holds original col c(p) = ((p>>1)&31) + 32*(2*(p>>6) + (p&1))
__global__ void prep_weights(const float* __restrict__ w, unsigned short* __restrict__ out,
                             int K, int permute) {
    int idx = blockIdx.x * blockDim.x + threadIdx.x;
    int total = K * 128;
    if (idx >= total) return;
    int j    = idx & 7;
    int lane = (idx >> 3) & 63;
    int t    = (idx >> 9) & 3;
    int s    = idx >> 11;
    int k = s * 16 + ((lane >> 5) << 3) + j;
    if (permute && k >= 128) {
        int p = k - 128;
        k = 128 + ((p >> 1) & 31) + 32 * (2 * (p >> 6) + (p & 1));
    }
    int n = t * 32 + (lane & 31);
    out[idx] = f32_to_bf16_rne(w[k * 128 + n]);
}

// ---------- xform kernel: XT = x @ W_top, XB = x @ W_bot + b1, bf16 [node][256] ----------
__launch_bounds__(256, 2)
__global__ void xform_kernel(const float* __restrict__ x, const short8* __restrict__ w1f,
                             const float* __restrict__ b1, unsigned short* __restrict__ xtb) {
    __shared__ __align__(16) short h1[4][32 * 136];
    const int wave = threadIdx.x >> 6;
    const int lane = threadIdx.x & 63;
    const int l31  = lane & 31;
    const int half = lane >> 5;
    short* hl = h1[wave];

    const int nbase = (blockIdx.x * 4 + wave) * 32;
    const int n = min(nbase + l31, N_NODES - 1);
    const float* px = x + (size_t)n * D + half * 8;

    union { short8 v; uint32_t u[4]; } fa[8];
#pragma unroll
    for (int s = 0; s < 8; ++s) {
        const int off = s * 16;
        float4 a0 = *(const float4*)(px + off);
        float4 a1 = *(const float4*)(px + off + 4);
        fa[s].u[0] = pack_bf16_rne(a0.x, a0.y); fa[s].u[1] = pack_bf16_rne(a0.z, a0.w);
        fa[s].u[2] = pack_bf16_rne(a1.x, a1.y); fa[s].u[3] = pack_bf16_rne(a1.z, a1.w);
    }

#pragma unroll
    for (int p = 0; p < 2; ++p) {
        floatx16 acc[4];
#pragma unroll
        for (int t = 0; t < 4; ++t) acc[t] = (floatx16)0.0f;
#pragma unroll
        for (int s = 0; s < 8; ++s) {
#pragma unroll
            for (int t = 0; t < 4; ++t) {
                short8 wf = w1f[((p * 8 + s) * 4 + t) * 64 + lane];
                acc[t] = __builtin_amdgcn_mfma_f32_32x32x16_bf16(fa[s].v, wf, acc[t], 0, 0, 0);
            }
        }
#pragma unroll
        for (int t = 0; t < 4; ++t) {
            float bias = p ? b1[t * 32 + l31] : 0.0f;
#pragma unroll
            for (int r = 0; r < 16; ++r) {
                int m = (r & 3) + 8 * (r >> 2) + 4 * half;
                hl[m * 136 + t * 32 + l31] = (short)f32_to_bf16_rne(acc[t][r] + bias);
            }
        }
#pragma unroll
        for (int it = 0; it < 8; ++it) {
            int off = it * 512 + lane * 8;
            int row = off >> 7;
            int col = off & 127;
            if (nbase + row < N_NODES) {
                short8 v = *(const short8*)(hl + row * 136 + col);
                *(short8*)(xtb + (size_t)(nbase + row) * 256 + p * 128 + col) = v;
            }
        }
    }
}

// ---------- message kernel: sorted edges; gather, ReLU, GEMM2, run-merged pk_add scatter ----------
__launch_bounds__(256, 4)
__global__ void msg_kernel(const unsigned short* __restrict__ xtb,
                           const int* __restrict__ srow, const int* __restrict__ scol,
                           const short8* __restrict__ w2f,
                           const float* __restrict__ b2,
                           uint32_t* __restrict__ agg) {
    const int lane = threadIdx.x & 63;
    const int l31  = lane & 31;
    const int half = lane >> 5;

    const int ebase = (blockIdx.x * 4 + (threadIdx.x >> 6)) * 32;
    const int e  = ebase + l31;
    const int ec = min(e, N_EDGES - 1);
    const int rI = srow[ec];
    const int cI = scol[ec];

    const unsigned short* pt = xtb + (size_t)rI * 256 + half * 8;        // XT[row]
    const unsigned short* pb = xtb + (size_t)cI * 256 + 128 + half * 8;  // XB[col] (+b1 folded)

    floatx16 acc2[4];
#pragma unroll
    for (int t = 0; t < 4; ++t) acc2[t] = (floatx16)0.0f;

#pragma unroll
    for (int s = 0; s < 8; ++s) {
        union { short8 v; uint32_t u[4]; } ta, tb, h;
        ta.v = *(const short8*)(pt + s * 16);
        tb.v = *(const short8*)(pb + s * 16);
#pragma unroll
        for (int d = 0; d < 4; ++d) {
            uint32_t au = ta.u[d], bu = tb.u[d];
            float lo = __builtin_bit_cast(float, au << 16) + __builtin_bit_cast(float, bu << 16);
            float hi = __builtin_bit_cast(float, au & 0xffff0000u) +
                       __builtin_bit_cast(float, bu & 0xffff0000u);
            lo = fmaxf(lo, 0.0f);
            hi = fmaxf(hi, 0.0f);
            h.u[d] = pack_bf16_rne(lo, hi);
        }
#pragma unroll
        for (int t = 0; t < 4; ++t) {
            short8 wf = w2f[(s * 4 + t) * 64 + lane];
            acc2[t] = __builtin_amdgcn_mfma_f32_32x32x16_bf16(h.v, wf, acc2[t], 0, 0, 0);
        }
    }

    float bias2[4];
#pragma unroll
    for (int t = 0; t < 4; ++t) bias2[t] = b2[t * 32 + l31];

    // Run-merged scatter: edges sorted by destination, so consecutive rows in a
    // quad (m = 8q+4*half+i, i=0..3) often share a destination -> merge in fp32,
    // emit one pk_add pair per distinct destination per quad.
#pragma unroll
    for (int q = 0; q < 4; ++q) {
        const int mb = 8 * q + 4 * half;
        float rs0 = 0.f, rs1 = 0.f, rs2 = 0.f, rs3 = 0.f;
        int curc = -1;
        bool have = false;
#pragma unroll
        for (int i = 0; i < 4; ++i) {
            const int r = 4 * q + i;
            const bool valid = (ebase + mb + i) < N_EDGES;
            const int ci = __shfl(cI, mb + i, 32);
            const float v0 = acc2[0][r] + bias2[0];
            const float v1 = acc2[1][r] + bias2[1];
            const float v2 = acc2[2][r] + bias2[2];
            const float v3 = acc2[3][r] + bias2[3];
            if (valid) {
                if (have && ci == curc) {
                    rs0 += v0; rs1 += v1; rs2 += v2; rs3 += v3;
                } else {
                    if (have) {
                        uint32_t* dst = agg + (size_t)curc * 64 + l31;
                        atomic_pk_add_bf16(dst,      pack_bf16_rne(rs0, rs1));
                        atomic_pk_add_bf16(dst + 32, pack_bf16_rne(rs2, rs3));
                    }
                    curc = ci; rs0 = v0; rs1 = v1; rs2 = v2; rs3 = v3; have = true;
                }
            }
        }
        if (have) {
            uint32_t* dst = agg + (size_t)curc * 64 + l31;
            atomic_pk_add_bf16(dst,      pack_bf16_rne(rs0, rs1));
            atomic_pk_add_bf16(dst + 32, pack_bf16_rne(rs2, rs3));
        }
    }
}

// ---------- update kernel: 32 nodes per wave, bf16 agg input, fused LN + residual ----------
__launch_bounds__(256, 4)
__global__ void upd_kernel(const float* __restrict__ x, const unsigned short* __restrict__ aggB,
                           const short8* __restrict__ w1f, const short8* __restrict__ w2f,
                           const float* __restrict__ b1, const float* __restrict__ b2,
                           const float* __restrict__ gamma, const float* __restrict__ beta,
                           float* __restrict__ out) {
    __shared__ __align__(16) short h1[4][32 * 136];
    const int wave = threadIdx.x >> 6;
    const int lane = threadIdx.x & 63;
    const int l31  = lane & 31;
    const int half = lane >> 5;
    short* hl = h1[wave];

    const int nbase = (blockIdx.x * 4 + wave) * 32;
    const int n = min(nbase + l31, N_NODES - 1);

    const float* px = x + (size_t)n * D + half * 8;
    const unsigned short* pagg = aggB + (size_t)n * D + half * 8;

    floatx16 acc[4];
#pragma unroll
    for (int t = 0; t < 4; ++t) acc[t] = (floatx16)0.0f;

#pragma unroll
    for (int s = 0; s < 16; ++s) {
        union { short8 v; uint32_t u[4]; } fa;
        if (s < 8) {
            const int off = s * 16;
            float4 a0 = *(const float4*)(px + off);
            float4 a1 = *(const float4*)(px + off + 4);
            fa.u[0] = pack_bf16_rne(a0.x, a0.y); fa.u[1] = pack_bf16_rne(a0.z, a0.w);
            fa.u[2] = pack_bf16_rne(a1.x, a1.y); fa.u[3] = pack_bf16_rne(a1.z, a1.w);
        } else {
            fa.v = *(const short8*)(pagg + (s - 8) * 16);  // permuted layout; w1f matches
        }
#pragma unroll
        for (int t = 0; t < 4; ++t) {
            short8 wf = w1f[(s * 4 + t) * 64 + lane];
            acc[t] = __builtin_amdgcn_mfma_f32_32x32x16_bf16(fa.v, wf, acc[t], 0, 0, 0);
        }
    }

#pragma unroll
    for (int t = 0; t < 4; ++t) {
        float bias1 = b1[t * 32 + l31];
#pragma unroll
        for (int r = 0; r < 16; ++r) {
            int m = (r & 3) + 8 * (r >> 2) + 4 * half;
            float v = fmaxf(acc[t][r] + bias1, 0.0f);
            hl[m * 136 + t * 32 + l31] = (short)f32_to_bf16_rne(v);
        }
    }

    floatx16 acc2[4];
#pragma unroll
    for (int t = 0; t < 4; ++t) acc2[t] = (floatx16)0.0f;

#pragma unroll
    for (int s = 0; s < 8; ++s) {
        short8 af = *(const short8*)(hl + l31 * 136 + s * 16 + half * 8);
#pragma unroll
        for (int t = 0; t < 4; ++t) {
            short8 wf = w2f[(s * 4 + t) * 64 + lane];
            acc2[t] = __builtin_amdgcn_mfma_f32_32x32x16_bf16(af, wf, acc2[t], 0, 0, 0);
        }
    }

    float g4[4], be4[4], bias2[4];
#pragma unroll
    for (int t = 0; t < 4; ++t) {
        g4[t]    = gamma[t * 32 + l31];
        be4[t]   = beta[t * 32 + l31];
        bias2[t] = b2[t * 32 + l31];
    }

#pragma unroll
    for (int r = 0; r < 16; ++r) {
        float hv[4];
        float s1 = 0.0f, s2 = 0.0f;
#pragma unroll
        for (int t = 0; t < 4; ++t) {
            hv[t] = acc2[t][r] + bias2[t];
            s1 += hv[t];
            s2 += hv[t] * hv[t];
        }
#pragma unroll
        for (int mask = 1; mask < 32; mask <<= 1) {
            s1 += __shfl_xor(s1, mask);
            s2 += __shfl_xor(s2, mask);
        }
        float mean = s1 * (1.0f / 128.0f);
        float var  = s2 * (1.0f / 128.0f) - mean * mean;
        float rs   = rsqrtf(var + EPS);
        int m = (r & 3) + 8 * (r >> 2) + 4 * half;
        int node = nbase + m;
        if (node < N_NODES) {
            const float* xr = x + (size_t)node * D + l31;
            float* orow = out + (size_t)node * D + l31;
#pragma unroll
            for (int t = 0; t < 4; ++t) {
                float v = (hv[t] - mean) * rs * g4[t] + be4[t] + xr[t * 32];
                orow[t * 32] = v;
            }
        }
    }
}

// ---------- launch ----------
extern "C" void kernel_launch(void* const* d_in, const int* in_sizes, int n_in,
                              void* d_out, int out_size, void* d_ws, size_t ws_size,
                              hipStream_t stream) {
    const float* x     = (const float*)d_in[0];
    const int*   edge  = (const int*)d_in[1];
    const float* w_m1  = (const float*)d_in[2];
    const float* b_m1  = (const float*)d_in[3];
    const float* w_m2  = (const float*)d_in[4];
    const float* b_m2  = (const float*)d_in[5];
    const float* w_u1  = (const float*)d_in[6];
    const float* b_u1  = (const float*)d_in[7];
    const float* w_u2  = (const float*)d_in[8];
    const float* b_u2  = (const float*)d_in[9];
    const float* gamma = (const float*)d_in[10];
    const float* beta  = (const float*)d_in[11];
    float* out = (float*)d_out;

    char* ws = (char*)d_ws;
    size_t off = 0;
    auto alloc = [&](size_t bytes) { void* p = ws + off; off = (off + bytes + 15) & ~(size_t)15; return p; };

    unsigned short* xtb  = (unsigned short*)alloc((size_t)N_NODES * 256 * 2);  // XT | XB+b1
    unsigned short* aggB = (unsigned short*)alloc((size_t)N_NODES * D * 2);    // permuted bf16 agg
    unsigned short* wm1f = (unsigned short*)alloc(256 * 128 * 2);
    unsigned short* wm2f = (unsigned short*)alloc(128 * 128 * 2);
    unsigned short* wu1f = (unsigned short*)alloc(256 * 128 * 2);
    unsigned short* wu2f = (unsigned short*)alloc(128 * 128 * 2);
    int* count  = (int*)alloc((size_t)N_NODES * 4);
    int* base   = (int*)alloc((size_t)N_NODES * 4);
    int* cursor = (int*)alloc((size_t)N_NODES * 4);
    int* bsum   = (int*)alloc(256 * 4);
    int* srow   = (int*)alloc(((size_t)N_EDGES + 128) * 4);
    int* scol   = (int*)alloc(((size_t)N_EDGES + 128) * 4);

    const int* rowi = edge;            // edge_index[0]
    const int* coli = edge + N_EDGES;  // edge_index[1]
    const int NB = (N_NODES + SCAN_BS - 1) / SCAN_BS;  // 196 blocks

    (void)hipMemsetAsync(aggB, 0, (size_t)N_NODES * D * 2, stream);
    (void)hipMemsetAsync(count, 0, (size_t)N_NODES * 4, stream);

    prep_weights<<<(256 * 128 + 255) / 256, 256, 0, stream>>>(w_m1, wm1f, 256, 0);
    prep_weights<<<(128 * 128 + 255) / 256, 256, 0, stream>>>(w_m2, wm2f, 128, 0);
    prep_weights<<<(256 * 128 + 255) / 256, 256, 0, stream>>>(w_u1, wu1f, 256, 1);  // permuted agg half
    prep_weights<<<(128 * 128 + 255) / 256, 256, 0, stream>>>(w_u2, wu2f, 128, 0);

    // counting sort of edges by destination
    hist_kernel<<<(N_EDGES + 255) / 256, 256, 0, stream>>>(coli, count);
    scanA_kernel<<<NB, SCAN_BS, 0, stream>>>(count, base, bsum);
    scanB_kernel<<<1, 256, 0, stream>>>(bsum, NB);
    scanC_kernel<<<NB, SCAN_BS, 0, stream>>>(base, bsum, cursor);
    scatter_kernel<<<(N_EDGES + 255) / 256, 256, 0, stream>>>(rowi, coli, cursor, srow, scol);

    xform_kernel<<<(N_NODES + 127) / 128, 256, 0, stream>>>(
        x, (const short8*)wm1f, b_m1, xtb);
    msg_kernel<<<(N_EDGES + 127) / 128, 256, 0, stream>>>(
        xtb, srow, scol, (const short8*)wm2f, b_m2, (uint32_t*)aggB);
    upd_kernel<<<(N_NODES + 127) / 128, 256, 0, stream>>>(
        x, aggB, (const short8*)wu1f, (const short8*)wu2f, b_u1, b_u2, gamma, beta, out);
}

// Round 7
// 312.382 us; speedup vs baseline: 1.7207x; 1.1223x over previous
//
#include <hip/hip_runtime.h>
#include <hip/hip_bf16.h>
#include <stdint.h>

#define N_NODES 100000
#define N_EDGES 600000
#define D 128
#define EPS 1e-5f
#define SCAN_BS 512

typedef __attribute__((ext_vector_type(8))) short short8;
typedef __attribute__((ext_vector_type(16))) float floatx16;

// ---------- helpers ----------

__device__ __forceinline__ uint32_t pack_bf16_rne(float lo, float hi) {
    uint32_t ul = __builtin_bit_cast(uint32_t, lo);
    uint32_t uh = __builtin_bit_cast(uint32_t, hi);
    ul += 0x7fffu + ((ul >> 16) & 1u);
    uh += 0x7fffu + ((uh >> 16) & 1u);
    return (ul >> 16) | (uh & 0xffff0000u);
}

__device__ __forceinline__ unsigned short f32_to_bf16_rne(float f) {
    uint32_t u = __builtin_bit_cast(uint32_t, f);
    u += 0x7fffu + ((u >> 16) & 1u);
    return (unsigned short)(u >> 16);
}

// ---------- counting sort of edges by destination (col) -> CSR ----------

__global__ void hist_kernel(const int* __restrict__ col, int* __restrict__ count) {
    int e = blockIdx.x * blockDim.x + threadIdx.x;
    if (e < N_EDGES) atomicAdd(&count[col[e]], 1);
}

__global__ void scanA_kernel(const int* __restrict__ count, int* __restrict__ base,
                             int* __restrict__ bsum) {
    __shared__ int tmp[SCAN_BS];
    int g = blockIdx.x * SCAN_BS + threadIdx.x;
    int v = (g < N_NODES) ? count[g] : 0;
    tmp[threadIdx.x] = v;
    __syncthreads();
    int acc = v;
#pragma unroll
    for (int off = 1; off < SCAN_BS; off <<= 1) {
        int add = (threadIdx.x >= off) ? tmp[threadIdx.x - off] : 0;
        __syncthreads();
        acc += add;
        tmp[threadIdx.x] = acc;
        __syncthreads();
    }
    if (g < N_NODES) base[g] = acc - v;                 // exclusive within block
    if (threadIdx.x == SCAN_BS - 1) bsum[blockIdx.x] = acc;
}

__global__ void scanB_kernel(int* __restrict__ bsum, int nb) {
    __shared__ int tmp[256];
    int v = (threadIdx.x < nb) ? bsum[threadIdx.x] : 0;
    tmp[threadIdx.x] = v;
    __syncthreads();
    int acc = v;
#pragma unroll
    for (int off = 1; off < 256; off <<= 1) {
        int add = (threadIdx.x >= off) ? tmp[threadIdx.x - off] : 0;
        __syncthreads();
        acc += add;
        tmp[threadIdx.x] = acc;
        __syncthreads();
    }
    if (threadIdx.x < nb) bsum[threadIdx.x] = acc - v;  // exclusive block offsets
}

__global__ void scanC_kernel(int* __restrict__ base, const int* __restrict__ bsum,
                             int* __restrict__ cursor) {
    int g = blockIdx.x * SCAN_BS + threadIdx.x;
    if (g < N_NODES) {
        int b = base[g] + bsum[blockIdx.x];
        base[g] = b;
        cursor[g] = b;
    }
}

__global__ void scatter_kernel(const int* __restrict__ row, const int* __restrict__ col,
                               int* __restrict__ cursor, int* __restrict__ srow) {
    int e = blockIdx.x * blockDim.x + threadIdx.x;
    if (e < N_EDGES) {
        int p = atomicAdd(&cursor[col[e]], 1);
        srow[p] = row[e];
    }
}

// ---------- small precomputes: Wc = w_m2 @ w_u1[128:], vb = b_m2 @ w_u1[128:] ----------

__global__ void wc_kernel(const float* __restrict__ w2, const float* __restrict__ wu1,
                          float* __restrict__ wc) {
    int idx = blockIdx.x * blockDim.x + threadIdx.x;   // 128*128
    if (idx >= 128 * 128) return;
    int i = idx >> 7, n = idx & 127;
    float s = 0.0f;
    for (int k = 0; k < 128; ++k) s += w2[i * 128 + k] * wu1[(128 + k) * 128 + n];
    wc[idx] = s;
}

__global__ void vb_kernel(const float* __restrict__ b2, const float* __restrict__ wu1,
                          float* __restrict__ vb) {
    int n = threadIdx.x;
    if (n < 128) {
        float s = 0.0f;
        for (int k = 0; k < 128; ++k) s += b2[k] * wu1[(128 + k) * 128 + n];
        vb[n] = s;
    }
}

// ---------- weight re-layout into 32x32x16 MFMA B-fragment order ----------
// frag element (s, t, lane, j)  <->  w[k = s*16 + (lane>>5)*8 + j][n = t*32 + (lane&31)]
__global__ void prep_weights(const float* __restrict__ w, unsigned short* __restrict__ out, int K) {
    int idx = blockIdx.x * blockDim.x + threadIdx.x;
    int total = K * 128;
    if (idx >= total) return;
    int j    = idx & 7;
    int lane = (idx >> 3) & 63;
    int t    = (idx >> 9) & 3;
    int s    = idx >> 11;
    int k = s * 16 + ((lane >> 5) << 3) + j;
    int n = t * 32 + (lane & 31);
    out[idx] = f32_to_bf16_rne(w[k * 128 + n]);
}

// ---------- xform kernel: XT = x @ W_top, XB = x @ W_bot + b1, bf16 [node][256] ----------
__launch_bounds__(256, 2)
__global__ void xform_kernel(const float* __restrict__ x, const short8* __restrict__ w1f,
                             const float* __restrict__ b1, unsigned short* __restrict__ xtb) {
    __shared__ __align__(16) short h1[4][32 * 136];
    const int wave = threadIdx.x >> 6;
    const int lane = threadIdx.x & 63;
    const int l31  = lane & 31;
    const int half = lane >> 5;
    short* hl = h1[wave];

    const int nbase = (blockIdx.x * 4 + wave) * 32;
    const int n = min(nbase + l31, N_NODES - 1);
    const float* px = x + (size_t)n * D + half * 8;

    union { short8 v; uint32_t u[4]; } fa[8];
#pragma unroll
    for (int s = 0; s < 8; ++s) {
        const int off = s * 16;
        float4 a0 = *(const float4*)(px + off);
        float4 a1 = *(const float4*)(px + off + 4);
        fa[s].u[0] = pack_bf16_rne(a0.x, a0.y); fa[s].u[1] = pack_bf16_rne(a0.z, a0.w);
        fa[s].u[2] = pack_bf16_rne(a1.x, a1.y); fa[s].u[3] = pack_bf16_rne(a1.z, a1.w);
    }

#pragma unroll
    for (int p = 0; p < 2; ++p) {
        floatx16 acc[4];
#pragma unroll
        for (int t = 0; t < 4; ++t) acc[t] = (floatx16)0.0f;
#pragma unroll
        for (int s = 0; s < 8; ++s) {
#pragma unroll
            for (int t = 0; t < 4; ++t) {
                short8 wf = w1f[((p * 8 + s) * 4 + t) * 64 + lane];
                acc[t] = __builtin_amdgcn_mfma_f32_32x32x16_bf16(fa[s].v, wf, acc[t], 0, 0, 0);
            }
        }
#pragma unroll
        for (int t = 0; t < 4; ++t) {
            float bias = p ? b1[t * 32 + l31] : 0.0f;
#pragma unroll
            for (int r = 0; r < 16; ++r) {
                int m = (r & 3) + 8 * (r >> 2) + 4 * half;
                hl[m * 136 + t * 32 + l31] = (short)f32_to_bf16_rne(acc[t][r] + bias);
            }
        }
#pragma unroll
        for (int it = 0; it < 8; ++it) {
            int off = it * 512 + lane * 8;
            int row = off >> 7;
            int col = off & 127;
            if (nbase + row < N_NODES) {
                short8 v = *(const short8*)(hl + row * 136 + col);
                *(short8*)(xtb + (size_t)(nbase + row) * 256 + p * 128 + col) = v;
            }
        }
    }
}

// ---------- aggregation kernel: hsum[c] = sum_{e in CSR[c]} ReLU(XT[srow[e]] + XB[c]) ----------
// One wave per node; lane owns dword l (cols 2l, 2l+1). fp32 accumulate, no atomics.
__launch_bounds__(256, 8)
__global__ void agg_kernel(const uint32_t* __restrict__ xtb32,
                           const int* __restrict__ srow,
                           const int* __restrict__ base, const int* __restrict__ count,
                           uint32_t* __restrict__ hsum) {
    const int node = blockIdx.x * 4 + (threadIdx.x >> 6);
    const int lane = threadIdx.x & 63;
    if (node >= N_NODES) return;

    const uint32_t xbu = xtb32[(size_t)node * 128 + 64 + lane];   // XB half (+b1 folded)
    const float xb_lo = __builtin_bit_cast(float, xbu << 16);
    const float xb_hi = __builtin_bit_cast(float, xbu & 0xffff0000u);

    float s_lo = 0.0f, s_hi = 0.0f;
    int i = base[node];
    const int endi = i + count[node];
    for (; i + 1 < endi; i += 2) {          // 2-way for memory-level parallelism
        int r0 = srow[i], r1 = srow[i + 1];
        uint32_t a0 = xtb32[(size_t)r0 * 128 + lane];
        uint32_t a1 = xtb32[(size_t)r1 * 128 + lane];
        s_lo += fmaxf(__builtin_bit_cast(float, a0 << 16) + xb_lo, 0.0f);
        s_hi += fmaxf(__builtin_bit_cast(float, a0 & 0xffff0000u) + xb_hi, 0.0f);
        s_lo += fmaxf(__builtin_bit_cast(float, a1 << 16) + xb_lo, 0.0f);
        s_hi += fmaxf(__builtin_bit_cast(float, a1 & 0xffff0000u) + xb_hi, 0.0f);
    }
    if (i < endi) {
        int r0 = srow[i];
        uint32_t a0 = xtb32[(size_t)r0 * 128 + lane];
        s_lo += fmaxf(__builtin_bit_cast(float, a0 << 16) + xb_lo, 0.0f);
        s_hi += fmaxf(__builtin_bit_cast(float, a0 & 0xffff0000u) + xb_hi, 0.0f);
    }
    hsum[(size_t)node * 64 + lane] = pack_bf16_rne(s_lo, s_hi);   // row-major bf16 cols
}

// ---------- update kernel: acc = x@Wu1top + hsum@Wc + deg*vb + b_u1 -> ReLU -> @Wu2 -> LN ----------
__launch_bounds__(256, 4)
__global__ void upd_kernel(const float* __restrict__ x, const unsigned short* __restrict__ hsum,
                           const short8* __restrict__ wu1tf, const short8* __restrict__ wcf,
                           const short8* __restrict__ wu2f,
                           const float* __restrict__ b_u1, const float* __restrict__ vb,
                           const int* __restrict__ count,
                           const float* __restrict__ b_u2,
                           const float* __restrict__ gamma, const float* __restrict__ beta,
                           float* __restrict__ out) {
    __shared__ __align__(16) short h1[4][32 * 136];
    const int wave = threadIdx.x >> 6;
    const int lane = threadIdx.x & 63;
    const int l31  = lane & 31;
    const int half = lane >> 5;
    short* hl = h1[wave];

    const int nbase = (blockIdx.x * 4 + wave) * 32;
    const int n = min(nbase + l31, N_NODES - 1);

    const float* px = x + (size_t)n * D + half * 8;
    const unsigned short* ph = hsum + (size_t)n * D + half * 8;

    floatx16 acc[4];
#pragma unroll
    for (int t = 0; t < 4; ++t) acc[t] = (floatx16)0.0f;

#pragma unroll
    for (int s = 0; s < 16; ++s) {
        union { short8 v; uint32_t u[4]; } fa;
        const short8* bf;
        if (s < 8) {
            const int off = s * 16;
            float4 a0 = *(const float4*)(px + off);
            float4 a1 = *(const float4*)(px + off + 4);
            fa.u[0] = pack_bf16_rne(a0.x, a0.y); fa.u[1] = pack_bf16_rne(a0.z, a0.w);
            fa.u[2] = pack_bf16_rne(a1.x, a1.y); fa.u[3] = pack_bf16_rne(a1.z, a1.w);
            bf = wu1tf + (s * 4) * 64;
        } else {
            fa.v = *(const short8*)(ph + (s - 8) * 16);
            bf = wcf + ((s - 8) * 4) * 64;
        }
#pragma unroll
        for (int t = 0; t < 4; ++t) {
            short8 wf = bf[t * 64 + lane];
            acc[t] = __builtin_amdgcn_mfma_f32_32x32x16_bf16(fa.v, wf, acc[t], 0, 0, 0);
        }
    }

    float bu1[4], vbt[4];
#pragma unroll
    for (int t = 0; t < 4; ++t) {
        bu1[t] = b_u1[t * 32 + l31];
        vbt[t] = vb[t * 32 + l31];
    }

#pragma unroll
    for (int r = 0; r < 16; ++r) {
        int m = (r & 3) + 8 * (r >> 2) + 4 * half;
        float dg = (float)count[min(nbase + m, N_NODES - 1)];
#pragma unroll
        for (int t = 0; t < 4; ++t) {
            float v = fmaxf(acc[t][r] + bu1[t] + dg * vbt[t], 0.0f);
            hl[m * 136 + t * 32 + l31] = (short)f32_to_bf16_rne(v);
        }
    }

    floatx16 acc2[4];
#pragma unroll
    for (int t = 0; t < 4; ++t) acc2[t] = (floatx16)0.0f;

#pragma unroll
    for (int s = 0; s < 8; ++s) {
        short8 af = *(const short8*)(hl + l31 * 136 + s * 16 + half * 8);
#pragma unroll
        for (int t = 0; t < 4; ++t) {
            short8 wf = wu2f[(s * 4 + t) * 64 + lane];
            acc2[t] = __builtin_amdgcn_mfma_f32_32x32x16_bf16(af, wf, acc2[t], 0, 0, 0);
        }
    }

    float g4[4], be4[4], bias2[4];
#pragma unroll
    for (int t = 0; t < 4; ++t) {
        g4[t]    = gamma[t * 32 + l31];
        be4[t]   = beta[t * 32 + l31];
        bias2[t] = b_u2[t * 32 + l31];
    }

#pragma unroll
    for (int r = 0; r < 16; ++r) {
        float hv[4];
        float s1 = 0.0f, s2 = 0.0f;
#pragma unroll
        for (int t = 0; t < 4; ++t) {
            hv[t] = acc2[t][r] + bias2[t];
            s1 += hv[t];
            s2 += hv[t] * hv[t];
        }
#pragma unroll
        for (int mask = 1; mask < 32; mask <<= 1) {
            s1 += __shfl_xor(s1, mask);
            s2 += __shfl_xor(s2, mask);
        }
        float mean = s1 * (1.0f / 128.0f);
        float var  = s2 * (1.0f / 128.0f) - mean * mean;
        float rs   = rsqrtf(var + EPS);
        int m = (r & 3) + 8 * (r >> 2) + 4 * half;
        int node = nbase + m;
        if (node < N_NODES) {
            const float* xr = x + (size_t)node * D + l31;
            float* orow = out + (size_t)node * D + l31;
#pragma unroll
            for (int t = 0; t < 4; ++t) {
                float v = (hv[t] - mean) * rs * g4[t] + be4[t] + xr[t * 32];
                orow[t * 32] = v;
            }
        }
    }
}

// ---------- launch ----------
extern "C" void kernel_launch(void* const* d_in, const int* in_sizes, int n_in,
                              void* d_out, int out_size, void* d_ws, size_t ws_size,
                              hipStream_t stream) {
    const float* x     = (const float*)d_in[0];
    const int*   edge  = (const int*)d_in[1];
    const float* w_m1  = (const float*)d_in[2];
    const float* b_m1  = (const float*)d_in[3];
    const float* w_m2  = (const float*)d_in[4];
    const float* b_m2  = (const float*)d_in[5];
    const float* w_u1  = (const float*)d_in[6];
    const float* b_u1  = (const float*)d_in[7];
    const float* w_u2  = (const float*)d_in[8];
    const float* b_u2  = (const float*)d_in[9];
    const float* gamma = (const float*)d_in[10];
    const float* beta  = (const float*)d_in[11];
    float* out = (float*)d_out;

    char* ws = (char*)d_ws;
    size_t off = 0;
    auto alloc = [&](size_t bytes) { void* p = ws + off; off = (off + bytes + 15) & ~(size_t)15; return p; };

    unsigned short* xtb   = (unsigned short*)alloc((size_t)N_NODES * 256 * 2);  // XT | XB+b1
    unsigned short* hsumB = (unsigned short*)alloc((size_t)N_NODES * D * 2);    // bf16 hsum
    unsigned short* wm1f  = (unsigned short*)alloc(256 * 128 * 2);
    unsigned short* wu1tf = (unsigned short*)alloc(128 * 128 * 2);
    unsigned short* wcf   = (unsigned short*)alloc(128 * 128 * 2);
    unsigned short* wu2f  = (unsigned short*)alloc(128 * 128 * 2);
    float* wc    = (float*)alloc(128 * 128 * 4);
    float* vb    = (float*)alloc(128 * 4);
    int* count   = (int*)alloc((size_t)N_NODES * 4);
    int* base    = (int*)alloc((size_t)N_NODES * 4);
    int* cursor  = (int*)alloc((size_t)N_NODES * 4);
    int* bsum    = (int*)alloc(256 * 4);
    int* srow    = (int*)alloc((size_t)N_EDGES * 4);

    const int* rowi = edge;            // edge_index[0]
    const int* coli = edge + N_EDGES;  // edge_index[1]
    const int NB = (N_NODES + SCAN_BS - 1) / SCAN_BS;  // 196 blocks

    (void)hipMemsetAsync(count, 0, (size_t)N_NODES * 4, stream);

    // weight preprocessing
    prep_weights<<<(256 * 128 + 255) / 256, 256, 0, stream>>>(w_m1, wm1f, 256);
    prep_weights<<<(128 * 128 + 255) / 256, 256, 0, stream>>>(w_u1, wu1tf, 128);  // top 128 rows
    prep_weights<<<(128 * 128 + 255) / 256, 256, 0, stream>>>(w_u2, wu2f, 128);
    wc_kernel<<<(128 * 128 + 255) / 256, 256, 0, stream>>>(w_m2, w_u1, wc);
    vb_kernel<<<1, 128, 0, stream>>>(b_m2, w_u1, vb);
    prep_weights<<<(128 * 128 + 255) / 256, 256, 0, stream>>>(wc, wcf, 128);

    // counting sort of edges by destination -> CSR (base, count, srow)
    hist_kernel<<<(N_EDGES + 255) / 256, 256, 0, stream>>>(coli, count);
    scanA_kernel<<<NB, SCAN_BS, 0, stream>>>(count, base, bsum);
    scanB_kernel<<<1, 256, 0, stream>>>(bsum, NB);
    scanC_kernel<<<NB, SCAN_BS, 0, stream>>>(base, bsum, cursor);
    scatter_kernel<<<(N_EDGES + 255) / 256, 256, 0, stream>>>(rowi, coli, cursor, srow);

    xform_kernel<<<(N_NODES + 127) / 128, 256, 0, stream>>>(
        x, (const short8*)wm1f, b_m1, xtb);
    agg_kernel<<<(N_NODES + 3) / 4, 256, 0, stream>>>(
        (const uint32_t*)xtb, srow, base, count, (uint32_t*)hsumB);
    upd_kernel<<<(N_NODES + 127) / 128, 256, 0, stream>>>(
        x, hsumB, (const short8*)wu1tf, (const short8*)wcf, (const short8*)wu2f,
        b_u1, vb, count, b_u2, gamma, beta, out);
}

// Round 8
// 291.712 us; speedup vs baseline: 1.8427x; 1.0709x over previous
//
#include <hip/hip_runtime.h>
#include <hip/hip_bf16.h>
#include <stdint.h>

#define N_NODES 100000
#define N_EDGES 600000
#define D 128
#define EPS 1e-5f
#define SCAN_BS 512

typedef __attribute__((ext_vector_type(8))) short short8;
typedef __attribute__((ext_vector_type(16))) float floatx16;

// ---------- helpers ----------

__device__ __forceinline__ uint32_t pack_bf16_rne(float lo, float hi) {
    uint32_t ul = __builtin_bit_cast(uint32_t, lo);
    uint32_t uh = __builtin_bit_cast(uint32_t, hi);
    ul += 0x7fffu + ((ul >> 16) & 1u);
    uh += 0x7fffu + ((uh >> 16) & 1u);
    return (ul >> 16) | (uh & 0xffff0000u);
}

__device__ __forceinline__ unsigned short f32_to_bf16_rne(float f) {
    uint32_t u = __builtin_bit_cast(uint32_t, f);
    u += 0x7fffu + ((u >> 16) & 1u);
    return (unsigned short)(u >> 16);
}

__device__ __forceinline__ float bflo(uint32_t a) { return __builtin_bit_cast(float, a << 16); }
__device__ __forceinline__ float bfhi(uint32_t a) { return __builtin_bit_cast(float, a & 0xffff0000u); }

// ---------- counting sort of edges by destination (col) -> CSR ----------

__global__ void hist_kernel(const int* __restrict__ col, int* __restrict__ count) {
    int e = blockIdx.x * blockDim.x + threadIdx.x;
    if (e < N_EDGES) atomicAdd(&count[col[e]], 1);
}

__global__ void scanA_kernel(const int* __restrict__ count, int* __restrict__ base,
                             int* __restrict__ bsum) {
    __shared__ int tmp[SCAN_BS];
    int g = blockIdx.x * SCAN_BS + threadIdx.x;
    int v = (g < N_NODES) ? count[g] : 0;
    tmp[threadIdx.x] = v;
    __syncthreads();
    int acc = v;
#pragma unroll
    for (int off = 1; off < SCAN_BS; off <<= 1) {
        int add = (threadIdx.x >= off) ? tmp[threadIdx.x - off] : 0;
        __syncthreads();
        acc += add;
        tmp[threadIdx.x] = acc;
        __syncthreads();
    }
    if (g < N_NODES) base[g] = acc - v;                 // exclusive within block
    if (threadIdx.x == SCAN_BS - 1) bsum[blockIdx.x] = acc;
}

__global__ void scanB_kernel(int* __restrict__ bsum, int nb) {
    __shared__ int tmp[256];
    int v = (threadIdx.x < nb) ? bsum[threadIdx.x] : 0;
    tmp[threadIdx.x] = v;
    __syncthreads();
    int acc = v;
#pragma unroll
    for (int off = 1; off < 256; off <<= 1) {
        int add = (threadIdx.x >= off) ? tmp[threadIdx.x - off] : 0;
        __syncthreads();
        acc += add;
        tmp[threadIdx.x] = acc;
        __syncthreads();
    }
    if (threadIdx.x < nb) bsum[threadIdx.x] = acc - v;  // exclusive block offsets
}

__global__ void scanC_kernel(int* __restrict__ base, const int* __restrict__ bsum,
                             int* __restrict__ cursor) {
    int g = blockIdx.x * SCAN_BS + threadIdx.x;
    if (g < N_NODES) {
        int b = base[g] + bsum[blockIdx.x];
        base[g] = b;
        cursor[g] = b;
    }
}

__global__ void scatter_kernel(const int* __restrict__ row, const int* __restrict__ col,
                               int* __restrict__ cursor, int* __restrict__ srow) {
    int e = blockIdx.x * blockDim.x + threadIdx.x;
    if (e < N_EDGES) {
        int p = atomicAdd(&cursor[col[e]], 1);
        srow[p] = row[e];
    }
}

// ---------- ALL weight preprocessing in one kernel ----------
// frag element (s, t, lane, j)  <->  w[k = s*16 + (lane>>5)*8 + j][n = t*32 + (lane&31)]
// Segments: [0,32768) wm1f (K=256) | [32768,49152) wu1tf | [49152,65536) wu2f
//           [65536,81920) wcf = frag(w_m2 @ w_u1[128:]) | [81920,82048) vb = b_m2 @ w_u1[128:]
__global__ void prep_all(const float* __restrict__ w_m1, const float* __restrict__ w_u1,
                         const float* __restrict__ w_u2, const float* __restrict__ w_m2,
                         const float* __restrict__ b_m2,
                         unsigned short* __restrict__ wm1f, unsigned short* __restrict__ wu1tf,
                         unsigned short* __restrict__ wu2f, unsigned short* __restrict__ wcf,
                         float* __restrict__ vb) {
    int idx = blockIdx.x * blockDim.x + threadIdx.x;
    int i = idx, k, n;
    {
        // decode (valid for any segment after rebasing)
        int j    = i & 7;
        int lane = (i >> 3) & 63;
        int t    = (i >> 9) & 3;
        int s    = i >> 11;
        k = (s & 15) * 16 + ((lane >> 5) << 3) + j;   // (s&15): rebased below per segment
        n = t * 32 + (lane & 31);
    }
    if (idx < 32768) {
        int j = idx & 7, lane = (idx >> 3) & 63, t = (idx >> 9) & 3, s = idx >> 11;
        int kk = s * 16 + ((lane >> 5) << 3) + j;
        wm1f[idx] = f32_to_bf16_rne(w_m1[kk * 128 + t * 32 + (lane & 31)]);
    } else if (idx < 49152) {
        int ii = idx - 32768;
        int j = ii & 7, lane = (ii >> 3) & 63, t = (ii >> 9) & 3, s = ii >> 11;
        int kk = s * 16 + ((lane >> 5) << 3) + j;
        wu1tf[ii] = f32_to_bf16_rne(w_u1[kk * 128 + t * 32 + (lane & 31)]);
    } else if (idx < 65536) {
        int ii = idx - 49152;
        int j = ii & 7, lane = (ii >> 3) & 63, t = (ii >> 9) & 3, s = ii >> 11;
        int kk = s * 16 + ((lane >> 5) << 3) + j;
        wu2f[ii] = f32_to_bf16_rne(w_u2[kk * 128 + t * 32 + (lane & 31)]);
    } else if (idx < 81920) {
        int ii = idx - 65536;
        int j = ii & 7, lane = (ii >> 3) & 63, t = (ii >> 9) & 3, s = ii >> 11;
        int kk = s * 16 + ((lane >> 5) << 3) + j;
        int nn = t * 32 + (lane & 31);
        float acc = 0.0f;
        for (int q = 0; q < 128; ++q)
            acc += w_m2[kk * 128 + q] * w_u1[(128 + q) * 128 + nn];
        wcf[ii] = f32_to_bf16_rne(acc);
    } else if (idx < 82048) {
        int nn = idx - 81920;
        float acc = 0.0f;
        for (int q = 0; q < 128; ++q)
            acc += b_m2[q] * w_u1[(128 + q) * 128 + nn];
        vb[nn] = acc;
    }
}

// ---------- xform kernel: XT = x @ W_top, XB = x @ W_bot + b1, bf16 [node][256] ----------
__launch_bounds__(256, 4)
__global__ void xform_kernel(const float* __restrict__ x, const short8* __restrict__ w1f,
                             const float* __restrict__ b1, unsigned short* __restrict__ xtb) {
    __shared__ __align__(16) short h1[4][32 * 136];
    const int wave = threadIdx.x >> 6;
    const int lane = threadIdx.x & 63;
    const int l31  = lane & 31;
    const int half = lane >> 5;
    short* hl = h1[wave];

    const int nbase = (blockIdx.x * 4 + wave) * 32;
    const int n = min(nbase + l31, N_NODES - 1);
    const float* px = x + (size_t)n * D + half * 8;

    union { short8 v; uint32_t u[4]; } fa[8];
#pragma unroll
    for (int s = 0; s < 8; ++s) {
        const int off = s * 16;
        float4 a0 = *(const float4*)(px + off);
        float4 a1 = *(const float4*)(px + off + 4);
        fa[s].u[0] = pack_bf16_rne(a0.x, a0.y); fa[s].u[1] = pack_bf16_rne(a0.z, a0.w);
        fa[s].u[2] = pack_bf16_rne(a1.x, a1.y); fa[s].u[3] = pack_bf16_rne(a1.z, a1.w);
    }

#pragma unroll
    for (int p = 0; p < 2; ++p) {
        floatx16 acc[4];
#pragma unroll
        for (int t = 0; t < 4; ++t) acc[t] = (floatx16)0.0f;
#pragma unroll
        for (int s = 0; s < 8; ++s) {
#pragma unroll
            for (int t = 0; t < 4; ++t) {
                short8 wf = w1f[((p * 8 + s) * 4 + t) * 64 + lane];
                acc[t] = __builtin_amdgcn_mfma_f32_32x32x16_bf16(fa[s].v, wf, acc[t], 0, 0, 0);
            }
        }
#pragma unroll
        for (int t = 0; t < 4; ++t) {
            float bias = p ? b1[t * 32 + l31] : 0.0f;
#pragma unroll
            for (int r = 0; r < 16; ++r) {
                int m = (r & 3) + 8 * (r >> 2) + 4 * half;
                hl[m * 136 + t * 32 + l31] = (short)f32_to_bf16_rne(acc[t][r] + bias);
            }
        }
#pragma unroll
        for (int it = 0; it < 8; ++it) {
            int off = it * 512 + lane * 8;
            int row = off >> 7;
            int col = off & 127;
            if (nbase + row < N_NODES) {
                short8 v = *(const short8*)(hl + row * 136 + col);
                *(short8*)(xtb + (size_t)(nbase + row) * 256 + p * 128 + col) = v;
            }
        }
    }
}

// ---------- aggregation: hsum[c] = sum_{e in CSR[c]} ReLU(XT[srow[e]] + XB[c]) ----------
// One wave per node. srow loaded lane-parallel (one coalesced load), broadcast by
// shuffle; gathers issued 4-deep for memory-level parallelism. fp32 accumulate.
__launch_bounds__(256, 8)
__global__ void agg_kernel(const uint32_t* __restrict__ xtb32,
                           const int* __restrict__ srow,
                           const int* __restrict__ base, const int* __restrict__ count,
                           uint32_t* __restrict__ hsum) {
    const int node = blockIdx.x * 4 + (threadIdx.x >> 6);
    const int lane = threadIdx.x & 63;
    if (node >= N_NODES) return;

    const int b   = base[node];
    const int deg = count[node];

    const uint32_t xbu = xtb32[(size_t)node * 128 + 64 + lane];   // XB half (+b1 folded)
    const float xb_lo = bflo(xbu);
    const float xb_hi = bfhi(xbu);

    float s_lo = 0.0f, s_hi = 0.0f;

    for (int t0 = 0; t0 < deg; t0 += 64) {
        const int nb = min(64, deg - t0);
        int sr = (lane < nb) ? srow[b + t0 + lane] : 0;
        int d = 0;
        for (; d + 4 <= nb; d += 4) {
            int r0 = __shfl(sr, d);
            int r1 = __shfl(sr, d + 1);
            int r2 = __shfl(sr, d + 2);
            int r3 = __shfl(sr, d + 3);
            uint32_t a0 = xtb32[(size_t)r0 * 128 + lane];
            uint32_t a1 = xtb32[(size_t)r1 * 128 + lane];
            uint32_t a2 = xtb32[(size_t)r2 * 128 + lane];
            uint32_t a3 = xtb32[(size_t)r3 * 128 + lane];
            s_lo += fmaxf(bflo(a0) + xb_lo, 0.0f); s_hi += fmaxf(bfhi(a0) + xb_hi, 0.0f);
            s_lo += fmaxf(bflo(a1) + xb_lo, 0.0f); s_hi += fmaxf(bfhi(a1) + xb_hi, 0.0f);
            s_lo += fmaxf(bflo(a2) + xb_lo, 0.0f); s_hi += fmaxf(bfhi(a2) + xb_hi, 0.0f);
            s_lo += fmaxf(bflo(a3) + xb_lo, 0.0f); s_hi += fmaxf(bfhi(a3) + xb_hi, 0.0f);
        }
        if (d + 2 <= nb) {
            int r0 = __shfl(sr, d);
            int r1 = __shfl(sr, d + 1);
            uint32_t a0 = xtb32[(size_t)r0 * 128 + lane];
            uint32_t a1 = xtb32[(size_t)r1 * 128 + lane];
            s_lo += fmaxf(bflo(a0) + xb_lo, 0.0f); s_hi += fmaxf(bfhi(a0) + xb_hi, 0.0f);
            s_lo += fmaxf(bflo(a1) + xb_lo, 0.0f); s_hi += fmaxf(bfhi(a1) + xb_hi, 0.0f);
            d += 2;
        }
        if (d < nb) {
            int r0 = __shfl(sr, d);
            uint32_t a0 = xtb32[(size_t)r0 * 128 + lane];
            s_lo += fmaxf(bflo(a0) + xb_lo, 0.0f); s_hi += fmaxf(bfhi(a0) + xb_hi, 0.0f);
        }
    }
    hsum[(size_t)node * 64 + lane] = pack_bf16_rne(s_lo, s_hi);
}

// ---------- update kernel: acc = x@Wu1top + hsum@Wc + deg*vb + b_u1 -> ReLU -> @Wu2 -> LN ----------
__launch_bounds__(256, 4)
__global__ void upd_kernel(const float* __restrict__ x, const unsigned short* __restrict__ hsum,
                           const short8* __restrict__ wu1tf, const short8* __restrict__ wcf,
                           const short8* __restrict__ wu2f,
                           const float* __restrict__ b_u1, const float* __restrict__ vb,
                           const int* __restrict__ count,
                           const float* __restrict__ b_u2,
                           const float* __restrict__ gamma, const float* __restrict__ beta,
                           float* __restrict__ out) {
    __shared__ __align__(16) short h1[4][32 * 136];
    const int wave = threadIdx.x >> 6;
    const int lane = threadIdx.x & 63;
    const int l31  = lane & 31;
    const int half = lane >> 5;
    short* hl = h1[wave];

    const int nbase = (blockIdx.x * 4 + wave) * 32;
    const int n = min(nbase + l31, N_NODES - 1);

    const float* px = x + (size_t)n * D + half * 8;
    const unsigned short* ph = hsum + (size_t)n * D + half * 8;

    floatx16 acc[4];
#pragma unroll
    for (int t = 0; t < 4; ++t) acc[t] = (floatx16)0.0f;

#pragma unroll
    for (int s = 0; s < 16; ++s) {
        union { short8 v; uint32_t u[4]; } fa;
        const short8* bf;
        if (s < 8) {
            const int off = s * 16;
            float4 a0 = *(const float4*)(px + off);
            float4 a1 = *(const float4*)(px + off + 4);
            fa.u[0] = pack_bf16_rne(a0.x, a0.y); fa.u[1] = pack_bf16_rne(a0.z, a0.w);
            fa.u[2] = pack_bf16_rne(a1.x, a1.y); fa.u[3] = pack_bf16_rne(a1.z, a1.w);
            bf = wu1tf + (s * 4) * 64;
        } else {
            fa.v = *(const short8*)(ph + (s - 8) * 16);
            bf = wcf + ((s - 8) * 4) * 64;
        }
#pragma unroll
        for (int t = 0; t < 4; ++t) {
            short8 wf = bf[t * 64 + lane];
            acc[t] = __builtin_amdgcn_mfma_f32_32x32x16_bf16(fa.v, wf, acc[t], 0, 0, 0);
        }
    }

    float bu1[4], vbt[4];
#pragma unroll
    for (int t = 0; t < 4; ++t) {
        bu1[t] = b_u1[t * 32 + l31];
        vbt[t] = vb[t * 32 + l31];
    }

#pragma unroll
    for (int r = 0; r < 16; ++r) {
        int m = (r & 3) + 8 * (r >> 2) + 4 * half;
        float dg = (float)count[min(nbase + m, N_NODES - 1)];
#pragma unroll
        for (int t = 0; t < 4; ++t) {
            float v = fmaxf(acc[t][r] + bu1[t] + dg * vbt[t], 0.0f);
            hl[m * 136 + t * 32 + l31] = (short)f32_to_bf16_rne(v);
        }
    }

    floatx16 acc2[4];
#pragma unroll
    for (int t = 0; t < 4; ++t) acc2[t] = (floatx16)0.0f;

#pragma unroll
    for (int s = 0; s < 8; ++s) {
        short8 af = *(const short8*)(hl + l31 * 136 + s * 16 + half * 8);
#pragma unroll
        for (int t = 0; t < 4; ++t) {
            short8 wf = wu2f[(s * 4 + t) * 64 + lane];
            acc2[t] = __builtin_amdgcn_mfma_f32_32x32x16_bf16(af, wf, acc2[t], 0, 0, 0);
        }
    }

    float g4[4], be4[4], bias2[4];
#pragma unroll
    for (int t = 0; t < 4; ++t) {
        g4[t]    = gamma[t * 32 + l31];
        be4[t]   = beta[t * 32 + l31];
        bias2[t] = b_u2[t * 32 + l31];
    }

#pragma unroll
    for (int r = 0; r < 16; ++r) {
        float hv[4];
        float s1 = 0.0f, s2 = 0.0f;
#pragma unroll
        for (int t = 0; t < 4; ++t) {
            hv[t] = acc2[t][r] + bias2[t];
            s1 += hv[t];
            s2 += hv[t] * hv[t];
        }
#pragma unroll
        for (int mask = 1; mask < 32; mask <<= 1) {
            s1 += __shfl_xor(s1, mask);
            s2 += __shfl_xor(s2, mask);
        }
        float mean = s1 * (1.0f / 128.0f);
        float var  = s2 * (1.0f / 128.0f) - mean * mean;
        float rs   = rsqrtf(var + EPS);
        int m = (r & 3) + 8 * (r >> 2) + 4 * half;
        int node = nbase + m;
        if (node < N_NODES) {
            const float* xr = x + (size_t)node * D + l31;
            float* orow = out + (size_t)node * D + l31;
#pragma unroll
            for (int t = 0; t < 4; ++t) {
                float v = (hv[t] - mean) * rs * g4[t] + be4[t] + xr[t * 32];
                orow[t * 32] = v;
            }
        }
    }
}

// ---------- launch ----------
extern "C" void kernel_launch(void* const* d_in, const int* in_sizes, int n_in,
                              void* d_out, int out_size, void* d_ws, size_t ws_size,
                              hipStream_t stream) {
    const float* x     = (const float*)d_in[0];
    const int*   edge  = (const int*)d_in[1];
    const float* w_m1  = (const float*)d_in[2];
    const float* b_m1  = (const float*)d_in[3];
    const float* w_m2  = (const float*)d_in[4];
    const float* b_m2  = (const float*)d_in[5];
    const float* w_u1  = (const float*)d_in[6];
    const float* b_u1  = (const float*)d_in[7];
    const float* w_u2  = (const float*)d_in[8];
    const float* b_u2  = (const float*)d_in[9];
    const float* gamma = (const float*)d_in[10];
    const float* beta  = (const float*)d_in[11];
    float* out = (float*)d_out;

    char* ws = (char*)d_ws;
    size_t off = 0;
    auto alloc = [&](size_t bytes) { void* p = ws + off; off = (off + bytes + 15) & ~(size_t)15; return p; };

    unsigned short* xtb   = (unsigned short*)alloc((size_t)N_NODES * 256 * 2);  // XT | XB+b1
    unsigned short* hsumB = (unsigned short*)alloc((size_t)N_NODES * D * 2);    // bf16 hsum
    unsigned short* wm1f  = (unsigned short*)alloc(256 * 128 * 2);
    unsigned short* wu1tf = (unsigned short*)alloc(128 * 128 * 2);
    unsigned short* wcf   = (unsigned short*)alloc(128 * 128 * 2);
    unsigned short* wu2f  = (unsigned short*)alloc(128 * 128 * 2);
    float* vb    = (float*)alloc(128 * 4);
    int* count   = (int*)alloc((size_t)N_NODES * 4);
    int* base    = (int*)alloc((size_t)N_NODES * 4);
    int* cursor  = (int*)alloc((size_t)N_NODES * 4);
    int* bsum    = (int*)alloc(256 * 4);
    int* srow    = (int*)alloc((size_t)N_EDGES * 4);

    const int* rowi = edge;            // edge_index[0]
    const int* coli = edge + N_EDGES;  // edge_index[1]
    const int NB = (N_NODES + SCAN_BS - 1) / SCAN_BS;  // 196 blocks

    (void)hipMemsetAsync(count, 0, (size_t)N_NODES * 4, stream);

    // ALL weight preprocessing in one launch
    prep_all<<<(82048 + 255) / 256, 256, 0, stream>>>(
        w_m1, w_u1, w_u2, w_m2, b_m2, wm1f, wu1tf, wu2f, wcf, vb);

    // counting sort of edges by destination -> CSR (base, count, srow)
    hist_kernel<<<(N_EDGES + 255) / 256, 256, 0, stream>>>(coli, count);
    scanA_kernel<<<NB, SCAN_BS, 0, stream>>>(count, base, bsum);
    scanB_kernel<<<1, 256, 0, stream>>>(bsum, NB);
    scanC_kernel<<<NB, SCAN_BS, 0, stream>>>(base, bsum, cursor);
    scatter_kernel<<<(N_EDGES + 255) / 256, 256, 0, stream>>>(rowi, coli, cursor, srow);

    xform_kernel<<<(N_NODES + 127) / 128, 256, 0, stream>>>(
        x, (const short8*)wm1f, b_m1, xtb);
    agg_kernel<<<(N_NODES + 3) / 4, 256, 0, stream>>>(
        (const uint32_t*)xtb, srow, base, count, (uint32_t*)hsumB);
    upd_kernel<<<(N_NODES + 127) / 128, 256, 0, stream>>>(
        x, hsumB, (const short8*)wu1tf, (const short8*)wcf, (const short8*)wu2f,
        b_u1, vb, count, b_u2, gamma, beta, out);
}

// Round 9
// 271.084 us; speedup vs baseline: 1.9829x; 1.0761x over previous
//
#include <hip/hip_runtime.h>
#include <hip/hip_bf16.h>
#include <stdint.h>

#define N_NODES 100000
#define N_EDGES 600000
#define D 128
#define EPS 1e-5f
#define SCAN_BS 512

#define PREP_BLOCKS 321            // (82048+255)/256
#define HIST_BLOCKS 2344           // (N_EDGES+255)/256
#define XF_BLOCKS   782            // (N_NODES+127)/128

typedef __attribute__((ext_vector_type(8))) short short8;
typedef __attribute__((ext_vector_type(16))) float floatx16;

// ---------- helpers ----------

__device__ __forceinline__ uint32_t pack_bf16_rne(float lo, float hi) {
    uint32_t ul = __builtin_bit_cast(uint32_t, lo);
    uint32_t uh = __builtin_bit_cast(uint32_t, hi);
    ul += 0x7fffu + ((ul >> 16) & 1u);
    uh += 0x7fffu + ((uh >> 16) & 1u);
    return (ul >> 16) | (uh & 0xffff0000u);
}

__device__ __forceinline__ unsigned short f32_to_bf16_rne(float f) {
    uint32_t u = __builtin_bit_cast(uint32_t, f);
    u += 0x7fffu + ((u >> 16) & 1u);
    return (unsigned short)(u >> 16);
}

__device__ __forceinline__ float bflo(uint32_t a) { return __builtin_bit_cast(float, a << 16); }
__device__ __forceinline__ float bfhi(uint32_t a) { return __builtin_bit_cast(float, a & 0xffff0000u); }

// ---------- K1: fused weight preprocessing + destination histogram ----------
// prep segments: [0,32768) wm1f (K=256) | [32768,49152) wu1tf | [49152,65536) wu2f
//                [65536,81920) wcf = frag(w_m2 @ w_u1[128:]) | [81920,82048) vb
__global__ void prep_hist(const float* __restrict__ w_m1, const float* __restrict__ w_u1,
                          const float* __restrict__ w_u2, const float* __restrict__ w_m2,
                          const float* __restrict__ b_m2,
                          unsigned short* __restrict__ wm1f, unsigned short* __restrict__ wu1tf,
                          unsigned short* __restrict__ wu2f, unsigned short* __restrict__ wcf,
                          float* __restrict__ vb,
                          const int* __restrict__ col, int* __restrict__ count) {
    if (blockIdx.x >= PREP_BLOCKS) {
        int e = (blockIdx.x - PREP_BLOCKS) * 256 + threadIdx.x;
        if (e < N_EDGES) atomicAdd(&count[col[e]], 1);
        return;
    }
    int idx = blockIdx.x * 256 + threadIdx.x;
    if (idx < 32768) {
        int j = idx & 7, lane = (idx >> 3) & 63, t = (idx >> 9) & 3, s = idx >> 11;
        int kk = s * 16 + ((lane >> 5) << 3) + j;
        wm1f[idx] = f32_to_bf16_rne(w_m1[kk * 128 + t * 32 + (lane & 31)]);
    } else if (idx < 49152) {
        int ii = idx - 32768;
        int j = ii & 7, lane = (ii >> 3) & 63, t = (ii >> 9) & 3, s = ii >> 11;
        int kk = s * 16 + ((lane >> 5) << 3) + j;
        wu1tf[ii] = f32_to_bf16_rne(w_u1[kk * 128 + t * 32 + (lane & 31)]);
    } else if (idx < 65536) {
        int ii = idx - 49152;
        int j = ii & 7, lane = (ii >> 3) & 63, t = (ii >> 9) & 3, s = ii >> 11;
        int kk = s * 16 + ((lane >> 5) << 3) + j;
        wu2f[ii] = f32_to_bf16_rne(w_u2[kk * 128 + t * 32 + (lane & 31)]);
    } else if (idx < 81920) {
        int ii = idx - 65536;
        int j = ii & 7, lane = (ii >> 3) & 63, t = (ii >> 9) & 3, s = ii >> 11;
        int kk = s * 16 + ((lane >> 5) << 3) + j;
        int nn = t * 32 + (lane & 31);
        float acc = 0.0f;
        for (int q = 0; q < 128; ++q)
            acc += w_m2[kk * 128 + q] * w_u1[(128 + q) * 128 + nn];
        wcf[ii] = f32_to_bf16_rne(acc);
    } else if (idx < 82048) {
        int nn = idx - 81920;
        float acc = 0.0f;
        for (int q = 0; q < 128; ++q)
            acc += b_m2[q] * w_u1[(128 + q) * 128 + nn];
        vb[nn] = acc;
    }
}

// ---------- K2: single-kernel scan. CSR slice order is irrelevant -> block base
// comes from an atomic global cursor instead of an ordered cross-block scan.
__global__ void scan_one(const int* __restrict__ count, int* __restrict__ base,
                         int* __restrict__ cursor, int* __restrict__ gcur) {
    __shared__ int tmp[SCAN_BS];
    __shared__ int bbase;
    int g = blockIdx.x * SCAN_BS + threadIdx.x;
    int v = (g < N_NODES) ? count[g] : 0;
    tmp[threadIdx.x] = v;
    __syncthreads();
    int acc = v;
#pragma unroll
    for (int off = 1; off < SCAN_BS; off <<= 1) {
        int add = (threadIdx.x >= off) ? tmp[threadIdx.x - off] : 0;
        __syncthreads();
        acc += add;
        tmp[threadIdx.x] = acc;
        __syncthreads();
    }
    if (threadIdx.x == SCAN_BS - 1) bbase = atomicAdd(gcur, acc);  // block total
    __syncthreads();
    if (g < N_NODES) {
        int b = bbase + acc - v;
        base[g] = b;
        cursor[g] = b;
    }
}

// ---------- K3: fused xform (XT|XB+b1 bf16 [node][256]) + edge scatter ----------
__launch_bounds__(256, 4)
__global__ void xform_scatter(const float* __restrict__ x, const short8* __restrict__ w1f,
                              const float* __restrict__ b1, unsigned short* __restrict__ xtb,
                              const int* __restrict__ row, const int* __restrict__ col,
                              int* __restrict__ cursor, int* __restrict__ srow) {
    if (blockIdx.x >= XF_BLOCKS) {
        int e = (blockIdx.x - XF_BLOCKS) * 256 + threadIdx.x;
        if (e < N_EDGES) {
            int p = atomicAdd(&cursor[col[e]], 1);
            srow[p] = row[e];
        }
        return;
    }

    __shared__ __align__(16) short h1[4][32 * 136];
    const int wave = threadIdx.x >> 6;
    const int lane = threadIdx.x & 63;
    const int l31  = lane & 31;
    const int half = lane >> 5;
    short* hl = h1[wave];

    const int nbase = (blockIdx.x * 4 + wave) * 32;
    const int n = min(nbase + l31, N_NODES - 1);
    const float* px = x + (size_t)n * D + half * 8;

    union { short8 v; uint32_t u[4]; } fa[8];
#pragma unroll
    for (int s = 0; s < 8; ++s) {
        const int off = s * 16;
        float4 a0 = *(const float4*)(px + off);
        float4 a1 = *(const float4*)(px + off + 4);
        fa[s].u[0] = pack_bf16_rne(a0.x, a0.y); fa[s].u[1] = pack_bf16_rne(a0.z, a0.w);
        fa[s].u[2] = pack_bf16_rne(a1.x, a1.y); fa[s].u[3] = pack_bf16_rne(a1.z, a1.w);
    }

#pragma unroll
    for (int p = 0; p < 2; ++p) {
        floatx16 acc[4];
#pragma unroll
        for (int t = 0; t < 4; ++t) acc[t] = (floatx16)0.0f;
#pragma unroll
        for (int s = 0; s < 8; ++s) {
#pragma unroll
            for (int t = 0; t < 4; ++t) {
                short8 wf = w1f[((p * 8 + s) * 4 + t) * 64 + lane];
                acc[t] = __builtin_amdgcn_mfma_f32_32x32x16_bf16(fa[s].v, wf, acc[t], 0, 0, 0);
            }
        }
#pragma unroll
        for (int t = 0; t < 4; ++t) {
            float bias = p ? b1[t * 32 + l31] : 0.0f;
#pragma unroll
            for (int r = 0; r < 16; ++r) {
                int m = (r & 3) + 8 * (r >> 2) + 4 * half;
                hl[m * 136 + t * 32 + l31] = (short)f32_to_bf16_rne(acc[t][r] + bias);
            }
        }
#pragma unroll
        for (int it = 0; it < 8; ++it) {
            int off = it * 512 + lane * 8;
            int r2 = off >> 7;
            int c2 = off & 127;
            if (nbase + r2 < N_NODES) {
                short8 v = *(const short8*)(hl + r2 * 136 + c2);
                *(short8*)(xtb + (size_t)(nbase + r2) * 256 + p * 128 + c2) = v;
            }
        }
    }
}

// ---------- aggregation: hsum[c] = sum_{e in CSR[c]} ReLU(XT[srow[e]] + XB[c]) ----------
__launch_bounds__(256, 8)
__global__ void agg_kernel(const uint32_t* __restrict__ xtb32,
                           const int* __restrict__ srow,
                           const int* __restrict__ base, const int* __restrict__ count,
                           uint32_t* __restrict__ hsum) {
    const int node = blockIdx.x * 4 + (threadIdx.x >> 6);
    const int lane = threadIdx.x & 63;
    if (node >= N_NODES) return;

    const int b   = base[node];
    const int deg = count[node];

    const uint32_t xbu = xtb32[(size_t)node * 128 + 64 + lane];
    const float xb_lo = bflo(xbu);
    const float xb_hi = bfhi(xbu);

    float s_lo = 0.0f, s_hi = 0.0f;

    for (int t0 = 0; t0 < deg; t0 += 64) {
        const int nb = min(64, deg - t0);
        int sr = (lane < nb) ? srow[b + t0 + lane] : 0;
        int d = 0;
        for (; d + 4 <= nb; d += 4) {
            int r0 = __shfl(sr, d);
            int r1 = __shfl(sr, d + 1);
            int r2 = __shfl(sr, d + 2);
            int r3 = __shfl(sr, d + 3);
            uint32_t a0 = xtb32[(size_t)r0 * 128 + lane];
            uint32_t a1 = xtb32[(size_t)r1 * 128 + lane];
            uint32_t a2 = xtb32[(size_t)r2 * 128 + lane];
            uint32_t a3 = xtb32[(size_t)r3 * 128 + lane];
            s_lo += fmaxf(bflo(a0) + xb_lo, 0.0f); s_hi += fmaxf(bfhi(a0) + xb_hi, 0.0f);
            s_lo += fmaxf(bflo(a1) + xb_lo, 0.0f); s_hi += fmaxf(bfhi(a1) + xb_hi, 0.0f);
            s_lo += fmaxf(bflo(a2) + xb_lo, 0.0f); s_hi += fmaxf(bfhi(a2) + xb_hi, 0.0f);
            s_lo += fmaxf(bflo(a3) + xb_lo, 0.0f); s_hi += fmaxf(bfhi(a3) + xb_hi, 0.0f);
        }
        if (d + 2 <= nb) {
            int r0 = __shfl(sr, d);
            int r1 = __shfl(sr, d + 1);
            uint32_t a0 = xtb32[(size_t)r0 * 128 + lane];
            uint32_t a1 = xtb32[(size_t)r1 * 128 + lane];
            s_lo += fmaxf(bflo(a0) + xb_lo, 0.0f); s_hi += fmaxf(bfhi(a0) + xb_hi, 0.0f);
            s_lo += fmaxf(bflo(a1) + xb_lo, 0.0f); s_hi += fmaxf(bfhi(a1) + xb_hi, 0.0f);
            d += 2;
        }
        if (d < nb) {
            int r0 = __shfl(sr, d);
            uint32_t a0 = xtb32[(size_t)r0 * 128 + lane];
            s_lo += fmaxf(bflo(a0) + xb_lo, 0.0f); s_hi += fmaxf(bfhi(a0) + xb_hi, 0.0f);
        }
    }
    hsum[(size_t)node * 64 + lane] = pack_bf16_rne(s_lo, s_hi);
}

// ---------- update: acc = x@Wu1top + hsum@Wc + deg*vb + b_u1 -> ReLU -> @Wu2 -> LN ----------
__launch_bounds__(256, 4)
__global__ void upd_kernel(const float* __restrict__ x, const unsigned short* __restrict__ hsum,
                           const short8* __restrict__ wu1tf, const short8* __restrict__ wcf,
                           const short8* __restrict__ wu2f,
                           const float* __restrict__ b_u1, const float* __restrict__ vb,
                           const int* __restrict__ count,
                           const float* __restrict__ b_u2,
                           const float* __restrict__ gamma, const float* __restrict__ beta,
                           float* __restrict__ out) {
    __shared__ __align__(16) short h1[4][32 * 136];
    const int wave = threadIdx.x >> 6;
    const int lane = threadIdx.x & 63;
    const int l31  = lane & 31;
    const int half = lane >> 5;
    short* hl = h1[wave];

    const int nbase = (blockIdx.x * 4 + wave) * 32;
    const int n = min(nbase + l31, N_NODES - 1);

    const float* px = x + (size_t)n * D + half * 8;
    const unsigned short* ph = hsum + (size_t)n * D + half * 8;

    // prefetch all hsum fragments (latency hidden under first-half MFMAs)
    short8 hfr[8];
#pragma unroll
    for (int s = 0; s < 8; ++s) hfr[s] = *(const short8*)(ph + s * 16);

    // per-row degree, loaded once lane-parallel, broadcast by shuffle
    float dgv = (float)count[min(nbase + l31, N_NODES - 1)];

    floatx16 acc[4];
#pragma unroll
    for (int t = 0; t < 4; ++t) acc[t] = (floatx16)0.0f;

#pragma unroll
    for (int s = 0; s < 16; ++s) {
        union { short8 v; uint32_t u[4]; } fa;
        const short8* bf;
        if (s < 8) {
            const int off = s * 16;
            float4 a0 = *(const float4*)(px + off);
            float4 a1 = *(const float4*)(px + off + 4);
            fa.u[0] = pack_bf16_rne(a0.x, a0.y); fa.u[1] = pack_bf16_rne(a0.z, a0.w);
            fa.u[2] = pack_bf16_rne(a1.x, a1.y); fa.u[3] = pack_bf16_rne(a1.z, a1.w);
            bf = wu1tf + (s * 4) * 64;
        } else {
            fa.v = hfr[s - 8];
            bf = wcf + ((s - 8) * 4) * 64;
        }
#pragma unroll
        for (int t = 0; t < 4; ++t) {
            short8 wf = bf[t * 64 + lane];
            acc[t] = __builtin_amdgcn_mfma_f32_32x32x16_bf16(fa.v, wf, acc[t], 0, 0, 0);
        }
    }

    float bu1[4], vbt[4];
#pragma unroll
    for (int t = 0; t < 4; ++t) {
        bu1[t] = b_u1[t * 32 + l31];
        vbt[t] = vb[t * 32 + l31];
    }

#pragma unroll
    for (int r = 0; r < 16; ++r) {
        int m = (r & 3) + 8 * (r >> 2) + 4 * half;
        float dg = __shfl(dgv, m, 32);
#pragma unroll
        for (int t = 0; t < 4; ++t) {
            float v = fmaxf(acc[t][r] + bu1[t] + dg * vbt[t], 0.0f);
            hl[m * 136 + t * 32 + l31] = (short)f32_to_bf16_rne(v);
        }
    }

    floatx16 acc2[4];
#pragma unroll
    for (int t = 0; t < 4; ++t) acc2[t] = (floatx16)0.0f;

#pragma unroll
    for (int s = 0; s < 8; ++s) {
        short8 af = *(const short8*)(hl + l31 * 136 + s * 16 + half * 8);
#pragma unroll
        for (int t = 0; t < 4; ++t) {
            short8 wf = wu2f[(s * 4 + t) * 64 + lane];
            acc2[t] = __builtin_amdgcn_mfma_f32_32x32x16_bf16(af, wf, acc2[t], 0, 0, 0);
        }
    }

    float g4[4], be4[4], bias2[4];
#pragma unroll
    for (int t = 0; t < 4; ++t) {
        g4[t]    = gamma[t * 32 + l31];
        be4[t]   = beta[t * 32 + l31];
        bias2[t] = b_u2[t * 32 + l31];
    }

    // LN epilogue via LDS (fp32, two 16-row passes reusing hl) -> float4 stores.
    float* hf = (float*)hl;   // 16 rows x 132 floats = 8448 B <= 8704 B wave slice
#pragma unroll
    for (int p = 0; p < 2; ++p) {
#pragma unroll
        for (int rr = 0; rr < 8; ++rr) {
            int r = p * 8 + rr;
            float hv[4];
            float s1 = 0.0f, s2 = 0.0f;
#pragma unroll
            for (int t = 0; t < 4; ++t) {
                hv[t] = acc2[t][r] + bias2[t];
                s1 += hv[t];
                s2 += hv[t] * hv[t];
            }
#pragma unroll
            for (int mask = 1; mask < 32; mask <<= 1) {
                s1 += __shfl_xor(s1, mask);
                s2 += __shfl_xor(s2, mask);
            }
            float mean = s1 * (1.0f / 128.0f);
            float var  = s2 * (1.0f / 128.0f) - mean * mean;
            float rs   = rsqrtf(var + EPS);
            int m = (r & 3) + 8 * (r >> 2) + 4 * half;   // pass p covers rows [16p, 16p+16)
            int mrow = m - 16 * p;
#pragma unroll
            for (int t = 0; t < 4; ++t)
                hf[mrow * 132 + t * 32 + l31] = (hv[t] - mean) * rs * g4[t] + be4[t];
        }
        // wave-private LDS: compiler orders via lgkmcnt, no barrier needed
#pragma unroll
        for (int it = 0; it < 8; ++it) {
            int q = it * 64 + lane;        // 512 float4 quads = 16 rows x 32
            int r2 = q >> 5;
            int c4 = q & 31;
            int node = nbase + 16 * p + r2;
            if (node < N_NODES) {
                float4 v = *(const float4*)(hf + r2 * 132 + c4 * 4);
                float4 xr = *(const float4*)(x + (size_t)node * D + c4 * 4);
                v.x += xr.x; v.y += xr.y; v.z += xr.z; v.w += xr.w;
                *(float4*)(out + (size_t)node * D + c4 * 4) = v;
            }
        }
    }
}

// ---------- launch ----------
extern "C" void kernel_launch(void* const* d_in, const int* in_sizes, int n_in,
                              void* d_out, int out_size, void* d_ws, size_t ws_size,
                              hipStream_t stream) {
    const float* x     = (const float*)d_in[0];
    const int*   edge  = (const int*)d_in[1];
    const float* w_m1  = (const float*)d_in[2];
    const float* b_m1  = (const float*)d_in[3];
    const float* w_m2  = (const float*)d_in[4];
    const float* b_m2  = (const float*)d_in[5];
    const float* w_u1  = (const float*)d_in[6];
    const float* b_u1  = (const float*)d_in[7];
    const float* w_u2  = (const float*)d_in[8];
    const float* b_u2  = (const float*)d_in[9];
    const float* gamma = (const float*)d_in[10];
    const float* beta  = (const float*)d_in[11];
    float* out = (float*)d_out;

    char* ws = (char*)d_ws;
    size_t off = 0;
    auto alloc = [&](size_t bytes) { void* p = ws + off; off = (off + bytes + 15) & ~(size_t)15; return p; };

    unsigned short* xtb   = (unsigned short*)alloc((size_t)N_NODES * 256 * 2);  // XT | XB+b1
    unsigned short* hsumB = (unsigned short*)alloc((size_t)N_NODES * D * 2);    // bf16 hsum
    unsigned short* wm1f  = (unsigned short*)alloc(256 * 128 * 2);
    unsigned short* wu1tf = (unsigned short*)alloc(128 * 128 * 2);
    unsigned short* wcf   = (unsigned short*)alloc(128 * 128 * 2);
    unsigned short* wu2f  = (unsigned short*)alloc(128 * 128 * 2);
    float* vb    = (float*)alloc(128 * 4);
    int* count   = (int*)alloc((size_t)N_NODES * 4 + 16);   // + gcur tail
    int* gcur    = count + N_NODES;
    int* base    = (int*)alloc((size_t)N_NODES * 4);
    int* cursor  = (int*)alloc((size_t)N_NODES * 4);
    int* srow    = (int*)alloc((size_t)N_EDGES * 4);

    const int* rowi = edge;            // edge_index[0]
    const int* coli = edge + N_EDGES;  // edge_index[1]
    const int NB = (N_NODES + SCAN_BS - 1) / SCAN_BS;  // 196 blocks

    (void)hipMemsetAsync(count, 0, (size_t)N_NODES * 4 + 16, stream);  // count + gcur

    // K1: all weight prep + destination histogram
    prep_hist<<<PREP_BLOCKS + HIST_BLOCKS, 256, 0, stream>>>(
        w_m1, w_u1, w_u2, w_m2, b_m2, wm1f, wu1tf, wu2f, wcf, vb, coli, count);

    // K2: single-kernel scan (block base via atomic cursor; CSR order irrelevant)
    scan_one<<<NB, SCAN_BS, 0, stream>>>(count, base, cursor, gcur);

    // K3: xform + edge scatter fused
    xform_scatter<<<XF_BLOCKS + HIST_BLOCKS, 256, 0, stream>>>(
        x, (const short8*)wm1f, b_m1, xtb, rowi, coli, cursor, srow);

    agg_kernel<<<(N_NODES + 3) / 4, 256, 0, stream>>>(
        (const uint32_t*)xtb, srow, base, count, (uint32_t*)hsumB);
    upd_kernel<<<(N_NODES + 127) / 128, 256, 0, stream>>>(
        x, hsumB, (const short8*)wu1tf, (const short8*)wcf, (const short8*)wu2f,
        b_u1, vb, count, b_u2, gamma, beta, out);
}

// Round 10
// 268.993 us; speedup vs baseline: 1.9983x; 1.0078x over previous
//
#include <hip/hip_runtime.h>
#include <hip/hip_bf16.h>
#include <stdint.h>

#define N_NODES 100000
#define N_EDGES 600000
#define D 128
#define EPS 1e-5f
#define SCAN_BS 512
#define ROW_MASK 0x1FFFF

#define PREP_BLOCKS 321            // (82048+255)/256
#define HIST_BLOCKS 2344           // (N_EDGES+255)/256
#define XF_BLOCKS   782            // (N_NODES+127)/128

typedef __attribute__((ext_vector_type(8))) short short8;
typedef __attribute__((ext_vector_type(16))) float floatx16;

// ---------- helpers ----------

__device__ __forceinline__ uint32_t pack_bf16_rne(float lo, float hi) {
    uint32_t ul = __builtin_bit_cast(uint32_t, lo);
    uint32_t uh = __builtin_bit_cast(uint32_t, hi);
    ul += 0x7fffu + ((ul >> 16) & 1u);
    uh += 0x7fffu + ((uh >> 16) & 1u);
    return (ul >> 16) | (uh & 0xffff0000u);
}

__device__ __forceinline__ unsigned short f32_to_bf16_rne(float f) {
    uint32_t u = __builtin_bit_cast(uint32_t, f);
    u += 0x7fffu + ((u >> 16) & 1u);
    return (unsigned short)(u >> 16);
}

__device__ __forceinline__ float bflo(uint32_t a) { return __builtin_bit_cast(float, a << 16); }
__device__ __forceinline__ float bfhi(uint32_t a) { return __builtin_bit_cast(float, a & 0xffff0000u); }

// ---------- K1: fused weight preprocessing + destination histogram ----------
__global__ void prep_hist(const float* __restrict__ w_m1, const float* __restrict__ w_u1,
                          const float* __restrict__ w_u2, const float* __restrict__ w_m2,
                          const float* __restrict__ b_m2,
                          unsigned short* __restrict__ wm1f, unsigned short* __restrict__ wu1tf,
                          unsigned short* __restrict__ wu2f, unsigned short* __restrict__ wcf,
                          float* __restrict__ vb,
                          const int* __restrict__ col, int* __restrict__ count) {
    if (blockIdx.x >= PREP_BLOCKS) {
        int e = (blockIdx.x - PREP_BLOCKS) * 256 + threadIdx.x;
        if (e < N_EDGES) atomicAdd(&count[col[e]], 1);
        return;
    }
    int idx = blockIdx.x * 256 + threadIdx.x;
    if (idx < 32768) {
        int j = idx & 7, lane = (idx >> 3) & 63, t = (idx >> 9) & 3, s = idx >> 11;
        int kk = s * 16 + ((lane >> 5) << 3) + j;
        wm1f[idx] = f32_to_bf16_rne(w_m1[kk * 128 + t * 32 + (lane & 31)]);
    } else if (idx < 49152) {
        int ii = idx - 32768;
        int j = ii & 7, lane = (ii >> 3) & 63, t = (ii >> 9) & 3, s = ii >> 11;
        int kk = s * 16 + ((lane >> 5) << 3) + j;
        wu1tf[ii] = f32_to_bf16_rne(w_u1[kk * 128 + t * 32 + (lane & 31)]);
    } else if (idx < 65536) {
        int ii = idx - 49152;
        int j = ii & 7, lane = (ii >> 3) & 63, t = (ii >> 9) & 3, s = ii >> 11;
        int kk = s * 16 + ((lane >> 5) << 3) + j;
        wu2f[ii] = f32_to_bf16_rne(w_u2[kk * 128 + t * 32 + (lane & 31)]);
    } else if (idx < 81920) {
        int ii = idx - 65536;
        int j = ii & 7, lane = (ii >> 3) & 63, t = (ii >> 9) & 3, s = ii >> 11;
        int kk = s * 16 + ((lane >> 5) << 3) + j;
        int nn = t * 32 + (lane & 31);
        float acc = 0.0f;
        for (int q = 0; q < 128; ++q)
            acc += w_m2[kk * 128 + q] * w_u1[(128 + q) * 128 + nn];
        wcf[ii] = f32_to_bf16_rne(acc);
    } else if (idx < 82048) {
        int nn = idx - 81920;
        float acc = 0.0f;
        for (int q = 0; q < 128; ++q)
            acc += b_m2[q] * w_u1[(128 + q) * 128 + nn];
        vb[nn] = acc;
    }
}

// ---------- K2: single-kernel scan (block base via atomic cursor; slice order irrelevant,
// but nodes within one 512-node scan block stay contiguous & ascending -> any 32-node
// group's CSR range is contiguous).
__global__ void scan_one(const int* __restrict__ count, int* __restrict__ base,
                         int* __restrict__ cursor, int* __restrict__ gcur) {
    __shared__ int tmp[SCAN_BS];
    __shared__ int bbase;
    int g = blockIdx.x * SCAN_BS + threadIdx.x;
    int v = (g < N_NODES) ? count[g] : 0;
    tmp[threadIdx.x] = v;
    __syncthreads();
    int acc = v;
#pragma unroll
    for (int off = 1; off < SCAN_BS; off <<= 1) {
        int add = (threadIdx.x >= off) ? tmp[threadIdx.x - off] : 0;
        __syncthreads();
        acc += add;
        tmp[threadIdx.x] = acc;
        __syncthreads();
    }
    if (threadIdx.x == SCAN_BS - 1) bbase = atomicAdd(gcur, acc);
    __syncthreads();
    if (g < N_NODES) {
        int b = bbase + acc - v;
        base[g] = b;
        cursor[g] = b;
    }
}

// ---------- K3: fused xform (XT|XB+b1 bf16 [node][256]) + packed edge scatter ----------
__launch_bounds__(256, 4)
__global__ void xform_scatter(const float* __restrict__ x, const short8* __restrict__ w1f,
                              const float* __restrict__ b1, unsigned short* __restrict__ xtb,
                              const int* __restrict__ row, const int* __restrict__ col,
                              int* __restrict__ cursor, int* __restrict__ srow) {
    if (blockIdx.x >= XF_BLOCKS) {
        int e = (blockIdx.x - XF_BLOCKS) * 256 + threadIdx.x;
        if (e < N_EDGES) {
            int c = col[e];
            int p = atomicAdd(&cursor[c], 1);
            srow[p] = row[e] | ((c & 31) << 17);   // row (17b) | node-in-group (5b)
        }
        return;
    }

    __shared__ __align__(16) short h1[4][32 * 136];
    const int wave = threadIdx.x >> 6;
    const int lane = threadIdx.x & 63;
    const int l31  = lane & 31;
    const int half = lane >> 5;
    short* hl = h1[wave];

    const int nbase = (blockIdx.x * 4 + wave) * 32;
    const int n = min(nbase + l31, N_NODES - 1);
    const float* px = x + (size_t)n * D + half * 8;

    union { short8 v; uint32_t u[4]; } fa[8];
#pragma unroll
    for (int s = 0; s < 8; ++s) {
        const int off = s * 16;
        float4 a0 = *(const float4*)(px + off);
        float4 a1 = *(const float4*)(px + off + 4);
        fa[s].u[0] = pack_bf16_rne(a0.x, a0.y); fa[s].u[1] = pack_bf16_rne(a0.z, a0.w);
        fa[s].u[2] = pack_bf16_rne(a1.x, a1.y); fa[s].u[3] = pack_bf16_rne(a1.z, a1.w);
    }

#pragma unroll
    for (int p = 0; p < 2; ++p) {
        floatx16 acc[4];
#pragma unroll
        for (int t = 0; t < 4; ++t) acc[t] = (floatx16)0.0f;
#pragma unroll
        for (int s = 0; s < 8; ++s) {
#pragma unroll
            for (int t = 0; t < 4; ++t) {
                short8 wf = w1f[((p * 8 + s) * 4 + t) * 64 + lane];
                acc[t] = __builtin_amdgcn_mfma_f32_32x32x16_bf16(fa[s].v, wf, acc[t], 0, 0, 0);
            }
        }
#pragma unroll
        for (int t = 0; t < 4; ++t) {
            float bias = p ? b1[t * 32 + l31] : 0.0f;
#pragma unroll
            for (int r = 0; r < 16; ++r) {
                int m = (r & 3) + 8 * (r >> 2) + 4 * half;
                hl[m * 136 + t * 32 + l31] = (short)f32_to_bf16_rne(acc[t][r] + bias);
            }
        }
#pragma unroll
        for (int it = 0; it < 8; ++it) {
            int off = it * 512 + lane * 8;
            int r2 = off >> 7;
            int c2 = off & 127;
            if (nbase + r2 < N_NODES) {
                short8 v = *(const short8*)(hl + r2 * 136 + c2);
                *(short8*)(xtb + (size_t)(nbase + r2) * 256 + p * 128 + c2) = v;
            }
        }
    }
}

// ---------- K4: fused aggregation + update ----------
// Phase A: wave streams its contiguous CSR slice (32 nodes), gathers XT[row]/XB[c]
//          8-deep, run-merges (destinations non-decreasing), flushes bf16 sums to LDS.
// Phase B: acc = x@Wu1top + hsumLDS@Wc + deg*vb + b_u1 -> ReLU -> @Wu2 -> LN -> +x.
__launch_bounds__(256, 4)
__global__ void upd_kernel(const float* __restrict__ x, const uint32_t* __restrict__ xtb32,
                           const int* __restrict__ srowpk,
                           const int* __restrict__ base, const int* __restrict__ count,
                           const short8* __restrict__ wu1tf, const short8* __restrict__ wcf,
                           const short8* __restrict__ wu2f,
                           const float* __restrict__ b_u1, const float* __restrict__ vb,
                           const float* __restrict__ b_u2,
                           const float* __restrict__ gamma, const float* __restrict__ beta,
                           float* __restrict__ out) {
    __shared__ __align__(16) short h1[4][32 * 136];
    const int wave = threadIdx.x >> 6;
    const int lane = threadIdx.x & 63;
    const int l31  = lane & 31;
    const int half = lane >> 5;
    short* hl = h1[wave];
    uint32_t* accu = (uint32_t*)hl;            // phase-A hsum: [32 nodes][64 dwords] = 8 KB

    const int nbase = (blockIdx.x * 4 + wave) * 32;
    const int nc = min(nbase + l31, N_NODES - 1);

    // per-row CSR info (lane-parallel), group range via shuffle
    const int b_l = base[nc];
    const int c_l = count[nc];
    const int ebeg = __shfl(b_l, 0);
    const int eend = __shfl(b_l, 31) + __shfl(c_l, 31);
    const float dgv = (float)c_l;

    // zero hsum rows (deg-0 nodes never flushed)
#pragma unroll
    for (int i = 0; i < 32; ++i) accu[i * 64 + lane] = 0;

    // ---- Phase A: edge stream, run-merged ----
    {
        float s_lo = 0.0f, s_hi = 0.0f;
        int curnib = -1;
        for (int t0 = ebeg; t0 < eend; t0 += 64) {
            const int nb = min(64, eend - t0);
            int pk = (lane < nb) ? srowpk[t0 + lane] : 0;
            for (int d = 0; d < nb; d += 4) {
                int p0 = __shfl(pk, d);
                int p1 = __shfl(pk, min(d + 1, nb - 1));
                int p2 = __shfl(pk, min(d + 2, nb - 1));
                int p3 = __shfl(pk, min(d + 3, nb - 1));
                int r0 = p0 & ROW_MASK, n0 = p0 >> 17;
                int r1 = p1 & ROW_MASK, n1 = p1 >> 17;
                int r2 = p2 & ROW_MASK, n2 = p2 >> 17;
                int r3 = p3 & ROW_MASK, n3 = p3 >> 17;
                uint32_t a0 = xtb32[(size_t)r0 * 128 + lane];
                uint32_t b0 = xtb32[(size_t)(nbase + n0) * 128 + 64 + lane];
                uint32_t a1 = xtb32[(size_t)r1 * 128 + lane];
                uint32_t b1v = xtb32[(size_t)(nbase + n1) * 128 + 64 + lane];
                uint32_t a2 = xtb32[(size_t)r2 * 128 + lane];
                uint32_t b2v = xtb32[(size_t)(nbase + n2) * 128 + 64 + lane];
                uint32_t a3 = xtb32[(size_t)r3 * 128 + lane];
                uint32_t b3v = xtb32[(size_t)(nbase + n3) * 128 + 64 + lane];

                {
                    float vlo = fmaxf(bflo(a0) + bflo(b0), 0.0f);
                    float vhi = fmaxf(bfhi(a0) + bfhi(b0), 0.0f);
                    if (n0 != curnib) {
                        if (curnib >= 0) accu[curnib * 64 + lane] = pack_bf16_rne(s_lo, s_hi);
                        curnib = n0; s_lo = vlo; s_hi = vhi;
                    } else { s_lo += vlo; s_hi += vhi; }
                }
                if (d + 1 < nb) {
                    float vlo = fmaxf(bflo(a1) + bflo(b1v), 0.0f);
                    float vhi = fmaxf(bfhi(a1) + bfhi(b1v), 0.0f);
                    if (n1 != curnib) {
                        accu[curnib * 64 + lane] = pack_bf16_rne(s_lo, s_hi);
                        curnib = n1; s_lo = vlo; s_hi = vhi;
                    } else { s_lo += vlo; s_hi += vhi; }
                }
                if (d + 2 < nb) {
                    float vlo = fmaxf(bflo(a2) + bflo(b2v), 0.0f);
                    float vhi = fmaxf(bfhi(a2) + bfhi(b2v), 0.0f);
                    if (n2 != curnib) {
                        accu[curnib * 64 + lane] = pack_bf16_rne(s_lo, s_hi);
                        curnib = n2; s_lo = vlo; s_hi = vhi;
                    } else { s_lo += vlo; s_hi += vhi; }
                }
                if (d + 3 < nb) {
                    float vlo = fmaxf(bflo(a3) + bflo(b3v), 0.0f);
                    float vhi = fmaxf(bfhi(a3) + bfhi(b3v), 0.0f);
                    if (n3 != curnib) {
                        accu[curnib * 64 + lane] = pack_bf16_rne(s_lo, s_hi);
                        curnib = n3; s_lo = vlo; s_hi = vhi;
                    } else { s_lo += vlo; s_hi += vhi; }
                }
            }
        }
        if (curnib >= 0) accu[curnib * 64 + lane] = pack_bf16_rne(s_lo, s_hi);
    }

    // ---- Phase B: GEMMs + LN (wave-private LDS; per-wave DS ordering suffices) ----
    const float* px = x + (size_t)nc * D + half * 8;

    floatx16 acc[4];
#pragma unroll
    for (int t = 0; t < 4; ++t) acc[t] = (floatx16)0.0f;

#pragma unroll
    for (int s = 0; s < 16; ++s) {
        union { short8 v; uint32_t u[4]; } fa;
        const short8* bf;
        if (s < 8) {
            const int off = s * 16;
            float4 a0 = *(const float4*)(px + off);
            float4 a1 = *(const float4*)(px + off + 4);
            fa.u[0] = pack_bf16_rne(a0.x, a0.y); fa.u[1] = pack_bf16_rne(a0.z, a0.w);
            fa.u[2] = pack_bf16_rne(a1.x, a1.y); fa.u[3] = pack_bf16_rne(a1.z, a1.w);
            bf = wu1tf + (s * 4) * 64;
        } else {
            fa.v = *(const short8*)((const short*)accu + l31 * 128 + (s - 8) * 16 + half * 8);
            bf = wcf + ((s - 8) * 4) * 64;
        }
#pragma unroll
        for (int t = 0; t < 4; ++t) {
            short8 wf = bf[t * 64 + lane];
            acc[t] = __builtin_amdgcn_mfma_f32_32x32x16_bf16(fa.v, wf, acc[t], 0, 0, 0);
        }
    }

    float bu1[4], vbt[4];
#pragma unroll
    for (int t = 0; t < 4; ++t) {
        bu1[t] = b_u1[t * 32 + l31];
        vbt[t] = vb[t * 32 + l31];
    }

#pragma unroll
    for (int r = 0; r < 16; ++r) {
        int m = (r & 3) + 8 * (r >> 2) + 4 * half;
        float dg = __shfl(dgv, m, 32);
#pragma unroll
        for (int t = 0; t < 4; ++t) {
            float v = fmaxf(acc[t][r] + bu1[t] + dg * vbt[t], 0.0f);
            hl[m * 136 + t * 32 + l31] = (short)f32_to_bf16_rne(v);
        }
    }

    floatx16 acc2[4];
#pragma unroll
    for (int t = 0; t < 4; ++t) acc2[t] = (floatx16)0.0f;

#pragma unroll
    for (int s = 0; s < 8; ++s) {
        short8 af = *(const short8*)(hl + l31 * 136 + s * 16 + half * 8);
#pragma unroll
        for (int t = 0; t < 4; ++t) {
            short8 wf = wu2f[(s * 4 + t) * 64 + lane];
            acc2[t] = __builtin_amdgcn_mfma_f32_32x32x16_bf16(af, wf, acc2[t], 0, 0, 0);
        }
    }

    float g4[4], be4[4], bias2[4];
#pragma unroll
    for (int t = 0; t < 4; ++t) {
        g4[t]    = gamma[t * 32 + l31];
        be4[t]   = beta[t * 32 + l31];
        bias2[t] = b_u2[t * 32 + l31];
    }

    // LN epilogue via LDS (fp32, two 16-row passes reusing hl) -> float4 stores.
    float* hf = (float*)hl;
#pragma unroll
    for (int p = 0; p < 2; ++p) {
#pragma unroll
        for (int rr = 0; rr < 8; ++rr) {
            int r = p * 8 + rr;
            float hv[4];
            float s1 = 0.0f, s2 = 0.0f;
#pragma unroll
            for (int t = 0; t < 4; ++t) {
                hv[t] = acc2[t][r] + bias2[t];
                s1 += hv[t];
                s2 += hv[t] * hv[t];
            }
#pragma unroll
            for (int mask = 1; mask < 32; mask <<= 1) {
                s1 += __shfl_xor(s1, mask);
                s2 += __shfl_xor(s2, mask);
            }
            float mean = s1 * (1.0f / 128.0f);
            float var  = s2 * (1.0f / 128.0f) - mean * mean;
            float rs   = rsqrtf(var + EPS);
            int m = (r & 3) + 8 * (r >> 2) + 4 * half;
            int mrow = m - 16 * p;
#pragma unroll
            for (int t = 0; t < 4; ++t)
                hf[mrow * 132 + t * 32 + l31] = (hv[t] - mean) * rs * g4[t] + be4[t];
        }
#pragma unroll
        for (int it = 0; it < 8; ++it) {
            int q = it * 64 + lane;
            int r2 = q >> 5;
            int c4 = q & 31;
            int node = nbase + 16 * p + r2;
            if (node < N_NODES) {
                float4 v = *(const float4*)(hf + r2 * 132 + c4 * 4);
                float4 xr = *(const float4*)(x + (size_t)node * D + c4 * 4);
                v.x += xr.x; v.y += xr.y; v.z += xr.z; v.w += xr.w;
                *(float4*)(out + (size_t)node * D + c4 * 4) = v;
            }
        }
    }
}

// ---------- launch ----------
extern "C" void kernel_launch(void* const* d_in, const int* in_sizes, int n_in,
                              void* d_out, int out_size, void* d_ws, size_t ws_size,
                              hipStream_t stream) {
    const float* x     = (const float*)d_in[0];
    const int*   edge  = (const int*)d_in[1];
    const float* w_m1  = (const float*)d_in[2];
    const float* b_m1  = (const float*)d_in[3];
    const float* w_m2  = (const float*)d_in[4];
    const float* b_m2  = (const float*)d_in[5];
    const float* w_u1  = (const float*)d_in[6];
    const float* b_u1  = (const float*)d_in[7];
    const float* w_u2  = (const float*)d_in[8];
    const float* b_u2  = (const float*)d_in[9];
    const float* gamma = (const float*)d_in[10];
    const float* beta  = (const float*)d_in[11];
    float* out = (float*)d_out;

    char* ws = (char*)d_ws;
    size_t off = 0;
    auto alloc = [&](size_t bytes) { void* p = ws + off; off = (off + bytes + 15) & ~(size_t)15; return p; };

    unsigned short* xtb   = (unsigned short*)alloc((size_t)N_NODES * 256 * 2);  // XT | XB+b1
    unsigned short* wm1f  = (unsigned short*)alloc(256 * 128 * 2);
    unsigned short* wu1tf = (unsigned short*)alloc(128 * 128 * 2);
    unsigned short* wcf   = (unsigned short*)alloc(128 * 128 * 2);
    unsigned short* wu2f  = (unsigned short*)alloc(128 * 128 * 2);
    float* vb    = (float*)alloc(128 * 4);
    int* count   = (int*)alloc((size_t)N_NODES * 4 + 16);   // + gcur tail
    int* gcur    = count + N_NODES;
    int* base    = (int*)alloc((size_t)N_NODES * 4);
    int* cursor  = (int*)alloc((size_t)N_NODES * 4);
    int* srow    = (int*)alloc((size_t)N_EDGES * 4);

    const int* rowi = edge;            // edge_index[0]
    const int* coli = edge + N_EDGES;  // edge_index[1]
    const int NB = (N_NODES + SCAN_BS - 1) / SCAN_BS;  // 196 blocks

    (void)hipMemsetAsync(count, 0, (size_t)N_NODES * 4 + 16, stream);  // count + gcur

    // K1: all weight prep + destination histogram
    prep_hist<<<PREP_BLOCKS + HIST_BLOCKS, 256, 0, stream>>>(
        w_m1, w_u1, w_u2, w_m2, b_m2, wm1f, wu1tf, wu2f, wcf, vb, coli, count);

    // K2: single-kernel scan
    scan_one<<<NB, SCAN_BS, 0, stream>>>(count, base, cursor, gcur);

    // K3: xform + packed edge scatter fused
    xform_scatter<<<XF_BLOCKS + HIST_BLOCKS, 256, 0, stream>>>(
        x, (const short8*)wm1f, b_m1, xtb, rowi, coli, cursor, srow);

    // K4: fused aggregation + update
    upd_kernel<<<(N_NODES + 127) / 128, 256, 0, stream>>>(
        x, (const uint32_t*)xtb, srow, base, count,
        (const short8*)wu1tf, (const short8*)wcf, (const short8*)wu2f,
        b_u1, vb, b_u2, gamma, beta, out);
}